// Round 3
// baseline (936.108 us; speedup 1.0000x reference)
//
#include <hip/hip_runtime.h>
#include <hip/hip_bf16.h>

#define NN 50000
#define EE 800000
#define EN (EE + NN)      // edges including self-loops
#define IN_DIM 128
#define HID 32
#define HEADS 4
#define F1 (HEADS * HID)  // 128
#define NEG 0.2f

typedef __hip_bfloat16 bf16;

__device__ __forceinline__ float cvt(float v) { return v; }
__device__ __forceinline__ float cvt(bf16 v)  { return __bfloat162float(v); }

// ---------------- dtype detector: flags[0]=float-is-f32, flags[1]=edge-is-i64 --
__global__ void k_detect(const unsigned* __restrict__ xw, const unsigned* __restrict__ ew,
                         int* __restrict__ flags) {
    if (threadIdx.x == 0 && blockIdx.x == 0) {
        // true-bf16 array: both halfwords are data bf16s (tame exponents, not all zero)
        // f32 array: low halfword = mantissa bits (random exps, some huge) OR all-zero
        //            (if values were bf16-rounded but stored as f32)
        int all_lo_zero = 1, huge = 0;
        for (int i = 0; i < 256; ++i) {
            unsigned lo = xw[i] & 0xFFFFu;
            if (lo != 0u) all_lo_zero = 0;
            unsigned ex = (lo >> 7) & 0xFFu;
            if (ex >= 0xC0u) huge = 1;     // |bf16| >= 2^65: implausible for data
        }
        flags[0] = (all_lo_zero || huge) ? 1 : 0;
        // int64 edges: every odd 32-bit word is a zero high-word (values < 50000)
        int i64 = 1;
        for (int i = 1; i < 256; i += 2) if (ew[i] != 0u) i64 = 0;
        flags[1] = i64;
    }
}

// ---------------- Layer 1 linear: h1(bf16) = x @ W1, plus attention logits ----
template <typename T>
__device__ __forceinline__ void lin1_body(const T* __restrict__ x, const T* __restrict__ W1,
                                          const T* __restrict__ as1, const T* __restrict__ ad1,
                                          bf16* __restrict__ h1, float* __restrict__ als,
                                          float* __restrict__ ald) {
    __shared__ float xs[IN_DIM];
    const int n = blockIdx.x, t = threadIdx.x;
    xs[t] = cvt(x[n * IN_DIM + t]);
    __syncthreads();
    float acc = 0.f;
#pragma unroll 8
    for (int k = 0; k < IN_DIM; ++k)
        acc += xs[k] * cvt(W1[k * F1 + t]);
    h1[n * F1 + t] = __float2bfloat16(acc);
    float ps = acc * cvt(as1[t]);
    float pd = acc * cvt(ad1[t]);
#pragma unroll
    for (int off = 16; off > 0; off >>= 1) {
        ps += __shfl_down(ps, off, 32);
        pd += __shfl_down(pd, off, 32);
    }
    if ((t & 31) == 0) {
        als[n * HEADS + (t >> 5)] = ps;
        ald[n * HEADS + (t >> 5)] = pd;
    }
}

__global__ void k_lin1(const void* x, const void* W1, const void* as1, const void* ad1,
                       const int* __restrict__ flags, bf16* h1, float* als, float* ald) {
    if (flags[0]) lin1_body<float>((const float*)x, (const float*)W1,
                                   (const float*)as1, (const float*)ad1, h1, als, ald);
    else          lin1_body<bf16>((const bf16*)x, (const bf16*)W1,
                                  (const bf16*)as1, (const bf16*)ad1, h1, als, ald);
}

// ---------------- edge index fetch --------------------------------------------
template <typename IT>
__device__ __forceinline__ void get_sd(const IT* __restrict__ ei, int idx, int& s, int& d) {
    if (idx < EE) { s = (int)ei[idx]; d = (int)ei[EE + idx]; }
    else          { s = d = idx - EE; }
}

// ---------------- Layer 1 edge pass 1: softmax denominators -------------------
template <typename IT>
__device__ __forceinline__ void edge1a_body(const IT* __restrict__ ei,
                                            const float4* __restrict__ als,
                                            const float4* __restrict__ ald,
                                            float* __restrict__ denom1) {
    int idx = blockIdx.x * blockDim.x + threadIdx.x;
    if (idx >= EN) return;
    int s, d; get_sd(ei, idx, s, d);
    float4 a = als[s], b = ald[d];
    float e0 = a.x + b.x, e1 = a.y + b.y, e2 = a.z + b.z, e3 = a.w + b.w;
    e0 = e0 > 0.f ? e0 : NEG * e0;
    e1 = e1 > 0.f ? e1 : NEG * e1;
    e2 = e2 > 0.f ? e2 : NEG * e2;
    e3 = e3 > 0.f ? e3 : NEG * e3;
    atomicAdd(&denom1[d * 4 + 0], __expf(e0));
    atomicAdd(&denom1[d * 4 + 1], __expf(e1));
    atomicAdd(&denom1[d * 4 + 2], __expf(e2));
    atomicAdd(&denom1[d * 4 + 3], __expf(e3));
}

__global__ void k_edge1a(const void* ei, const float4* als, const float4* ald,
                         const int* __restrict__ flags, float* denom1) {
    if (flags[1]) edge1a_body<long long>((const long long*)ei, als, ald, denom1);
    else          edge1a_body<int>((const int*)ei, als, ald, denom1);
}

// ---------------- Layer 1 edge pass 2: message scatter ------------------------
template <typename IT>
__device__ __forceinline__ void edge1b_body(const IT* __restrict__ ei,
                                            const float* __restrict__ als,
                                            const float* __restrict__ ald,
                                            const float* __restrict__ denom1,
                                            const bf16* __restrict__ h1,
                                            float* __restrict__ out1) {
    long long gid = (long long)blockIdx.x * blockDim.x + threadIdx.x;
    if (gid >= (long long)EN * 128) return;
    int edge = (int)(gid >> 7), col = (int)(gid & 127), h = col >> 5;
    int s, d; get_sd(ei, edge, s, d);
    float e = als[s * 4 + h] + ald[d * 4 + h];
    e = e > 0.f ? e : NEG * e;
    float alpha = __expf(e) / (denom1[d * 4 + h] + 1e-16f);
    atomicAdd(&out1[d * 128 + col], cvt(h1[s * 128 + col]) * alpha);
}

__global__ void k_edge1b(const void* ei, const float* als, const float* ald,
                         const float* denom1, const bf16* h1,
                         const int* __restrict__ flags, float* out1) {
    if (flags[1]) edge1b_body<long long>((const long long*)ei, als, ald, denom1, h1, out1);
    else          edge1b_body<int>((const int*)ei, als, ald, denom1, h1, out1);
}

// ---------------- Mid: bias + ELU, h2 = h_mid @ W2, layer-2 logits ------------
template <typename T>
__device__ __forceinline__ void mid_body(const float* __restrict__ out1,
                                         const T* __restrict__ b1, const T* __restrict__ W2,
                                         const T* __restrict__ as2, const T* __restrict__ ad2,
                                         float* __restrict__ h2, float* __restrict__ als2,
                                         float* __restrict__ ald2) {
    __shared__ float hm[F1];
    __shared__ float part[F1];
    const int n = blockIdx.x, t = threadIdx.x;
    float v = out1[n * F1 + t] + cvt(b1[t]);
    hm[t] = v > 0.f ? v : (__expf(v) - 1.f);   // ELU(alpha=1)
    __syncthreads();
    const int j = t & 31, q = t >> 5;
    float p = 0.f;
#pragma unroll
    for (int kk = 0; kk < 32; ++kk) {
        int k = q * 32 + kk;
        p += hm[k] * cvt(W2[k * HID + j]);
    }
    part[t] = p;
    __syncthreads();
    if (t < 32) {
        float hv = part[t] + part[32 + t] + part[64 + t] + part[96 + t];
        h2[n * HID + t] = hv;
        float ps = hv * cvt(as2[t]);
        float pd = hv * cvt(ad2[t]);
#pragma unroll
        for (int off = 16; off > 0; off >>= 1) {
            ps += __shfl_down(ps, off, 32);
            pd += __shfl_down(pd, off, 32);
        }
        if (t == 0) { als2[n] = ps; ald2[n] = pd; }
    }
}

__global__ void k_mid(const float* out1, const void* b1, const void* W2,
                      const void* as2, const void* ad2, const int* __restrict__ flags,
                      float* h2, float* als2, float* ald2) {
    if (flags[0]) mid_body<float>(out1, (const float*)b1, (const float*)W2,
                                  (const float*)as2, (const float*)ad2, h2, als2, ald2);
    else          mid_body<bf16>(out1, (const bf16*)b1, (const bf16*)W2,
                                 (const bf16*)as2, (const bf16*)ad2, h2, als2, ald2);
}

// ---------------- Layer 2 edge pass 1: denominators ---------------------------
template <typename IT>
__device__ __forceinline__ void edge2a_body(const IT* __restrict__ ei,
                                            const float* __restrict__ als2,
                                            const float* __restrict__ ald2,
                                            float* __restrict__ denom2) {
    int idx = blockIdx.x * blockDim.x + threadIdx.x;
    if (idx >= EN) return;
    int s, d; get_sd(ei, idx, s, d);
    float e = als2[s] + ald2[d];
    e = e > 0.f ? e : NEG * e;
    atomicAdd(&denom2[d], __expf(e));
}

__global__ void k_edge2a(const void* ei, const float* als2, const float* ald2,
                         const int* __restrict__ flags, float* denom2) {
    if (flags[1]) edge2a_body<long long>((const long long*)ei, als2, ald2, denom2);
    else          edge2a_body<int>((const int*)ei, als2, ald2, denom2);
}

// ---------------- Layer 2 edge pass 2: message scatter ------------------------
template <typename IT>
__device__ __forceinline__ void edge2b_body(const IT* __restrict__ ei,
                                            const float* __restrict__ als2,
                                            const float* __restrict__ ald2,
                                            const float* __restrict__ denom2,
                                            const float* __restrict__ h2,
                                            float* __restrict__ out2) {
    int gid = blockIdx.x * blockDim.x + threadIdx.x;
    if (gid >= EN * 32) return;
    int edge = gid >> 5, c = gid & 31;
    int s, d; get_sd(ei, edge, s, d);
    float e = als2[s] + ald2[d];
    e = e > 0.f ? e : NEG * e;
    float alpha = __expf(e) / (denom2[d] + 1e-16f);
    atomicAdd(&out2[d * 32 + c], h2[s * 32 + c] * alpha);
}

__global__ void k_edge2b(const void* ei, const float* als2, const float* ald2,
                         const float* denom2, const float* h2,
                         const int* __restrict__ flags, float* out2) {
    if (flags[1]) edge2b_body<long long>((const long long*)ei, als2, ald2, denom2, h2, out2);
    else          edge2b_body<int>((const int*)ei, als2, ald2, denom2, h2, out2);
}

// ---------------- Finalize: + b2, store in detected dtype ---------------------
__global__ void k_fin(const float* __restrict__ out2, const void* b2v,
                      const int* __restrict__ flags, void* out) {
    int gid = blockIdx.x * blockDim.x + threadIdx.x;
    if (gid >= NN * HID) return;
    int c = gid & 31;
    if (flags[0]) {
        float bb = ((const float*)b2v)[c];
        ((float*)out)[gid] = out2[gid] + bb;
    } else {
        float bb = cvt(((const bf16*)b2v)[c]);
        ((bf16*)out)[gid] = __float2bfloat16(out2[gid] + bb);
    }
}

extern "C" void kernel_launch(void* const* d_in, const int* in_sizes, int n_in,
                              void* d_out, int out_size, void* d_ws, size_t ws_size,
                              hipStream_t stream) {
    const void* x    = d_in[0];
    const void* ei   = d_in[1];
    const void* W1   = d_in[2];
    const void* a_s1 = d_in[3];
    const void* a_d1 = d_in[4];
    const void* b1   = d_in[5];
    const void* W2   = d_in[6];
    const void* a_s2 = d_in[7];
    const void* a_d2 = d_in[8];
    const void* b2v  = d_in[9];

    // ---- workspace layout: flags (256 B) then fp32 arrays, peak ~41.4 MB ----
    int*   flags  = (int*)d_ws;
    float* p      = (float*)d_ws + 64;
    float* outacc = p; p += (size_t)NN * F1;             // out1; reused as out2
    bf16*  h1     = (bf16*)p; p += (size_t)NN * F1 / 2;  // bf16; region reused as f32 h2
    float* h2     = (float*)h1;                          // alias (h1 dead when h2 written)
    float* al_s1  = p; p += (size_t)NN * HEADS;
    float* al_d1  = p; p += (size_t)NN * HEADS;
    float* denom1 = p; p += (size_t)NN * HEADS;
    float* al_s2  = p; p += NN;
    float* al_d2  = p; p += NN;
    float* denom2 = p; p += NN;
    float* out2   = outacc;

    hipMemsetAsync(outacc, 0, (size_t)NN * F1 * sizeof(float), stream);
    hipMemsetAsync(denom1, 0, (size_t)NN * HEADS * sizeof(float), stream);
    hipMemsetAsync(denom2, 0, (size_t)NN * sizeof(float), stream);

    k_detect<<<1, 64, 0, stream>>>((const unsigned*)x, (const unsigned*)ei, flags);
    k_lin1<<<NN, 128, 0, stream>>>(x, W1, a_s1, a_d1, flags, h1, al_s1, al_d1);
    k_edge1a<<<(EN + 255) / 256, 256, 0, stream>>>(ei, (const float4*)al_s1,
                                                   (const float4*)al_d1, flags, denom1);
    {
        long long tot = (long long)EN * 128;
        k_edge1b<<<(unsigned)((tot + 255) / 256), 256, 0, stream>>>(ei, al_s1, al_d1,
                                                                    denom1, h1, flags, outacc);
    }
    k_mid<<<NN, 128, 0, stream>>>(outacc, b1, W2, a_s2, a_d2, flags, h2, al_s2, al_d2);
    hipMemsetAsync(out2, 0, (size_t)NN * HID * sizeof(float), stream);
    k_edge2a<<<(EN + 255) / 256, 256, 0, stream>>>(ei, al_s2, al_d2, flags, denom2);
    k_edge2b<<<(EN * 32 + 255) / 256, 256, 0, stream>>>(ei, al_s2, al_d2, denom2, h2,
                                                        flags, out2);
    k_fin<<<(NN * HID + 255) / 256, 256, 0, stream>>>(out2, b2v, flags, d_out);
}

// Round 4
// 574.319 us; speedup vs baseline: 1.6299x; 1.6299x over previous
//
#include <hip/hip_runtime.h>
#include <hip/hip_bf16.h>

#define NN 50000
#define EE 800000
#define EN (EE + NN)      // edges including self-loops
#define IN_DIM 128
#define HID 32
#define HEADS 4
#define F1 (HEADS * HID)  // 128
#define NEG 0.2f

typedef __hip_bfloat16 bf16;

__device__ __forceinline__ float cvt(float v) { return v; }
__device__ __forceinline__ float cvt(bf16 v)  { return __bfloat162float(v); }

// ---------------- dtype detector: flags[0]=float-is-f32, flags[1]=edge-is-i64 --
__global__ void k_detect(const unsigned* __restrict__ xw, const unsigned* __restrict__ ew,
                         int* __restrict__ flags) {
    if (threadIdx.x == 0 && blockIdx.x == 0) {
        int all_lo_zero = 1, huge = 0;
        for (int i = 0; i < 256; ++i) {
            unsigned lo = xw[i] & 0xFFFFu;
            if (lo != 0u) all_lo_zero = 0;
            unsigned ex = (lo >> 7) & 0xFFu;
            if (ex >= 0xC0u) huge = 1;
        }
        flags[0] = (all_lo_zero || huge) ? 1 : 0;
        int i64 = 1;
        for (int i = 1; i < 256; i += 2) if (ew[i] != 0u) i64 = 0;
        flags[1] = i64;
    }
}

// ---------------- edge decode helpers ----------------------------------------
template <typename IT>
__device__ __forceinline__ int dst_of(const IT* __restrict__ ei, int idx) {
    return idx < EE ? (int)ei[EE + idx] : idx - EE;
}
template <typename IT>
__device__ __forceinline__ int src_of(const IT* __restrict__ ei, int eid) {
    return eid < EE ? (int)ei[eid] : eid - EE;
}

// ---------------- Layer 1 linear: h1(bf16) = x @ W1, plus attention logits ----
template <typename T>
__device__ __forceinline__ void lin1_body(const T* __restrict__ x, const T* __restrict__ W1,
                                          const T* __restrict__ as1, const T* __restrict__ ad1,
                                          bf16* __restrict__ h1, float* __restrict__ als,
                                          float* __restrict__ ald) {
    __shared__ float xs[IN_DIM];
    const int n = blockIdx.x, t = threadIdx.x;
    xs[t] = cvt(x[n * IN_DIM + t]);
    __syncthreads();
    float acc = 0.f;
#pragma unroll 8
    for (int k = 0; k < IN_DIM; ++k)
        acc += xs[k] * cvt(W1[k * F1 + t]);
    h1[n * F1 + t] = __float2bfloat16(acc);
    float ps = acc * cvt(as1[t]);
    float pd = acc * cvt(ad1[t]);
#pragma unroll
    for (int off = 16; off > 0; off >>= 1) {
        ps += __shfl_down(ps, off, 32);
        pd += __shfl_down(pd, off, 32);
    }
    if ((t & 31) == 0) {
        als[n * HEADS + (t >> 5)] = ps;
        ald[n * HEADS + (t >> 5)] = pd;
    }
}

__global__ void k_lin1(const void* x, const void* W1, const void* as1, const void* ad1,
                       const int* __restrict__ flags, bf16* h1, float* als, float* ald) {
    if (flags[0]) lin1_body<float>((const float*)x, (const float*)W1,
                                   (const float*)as1, (const float*)ad1, h1, als, ald);
    else          lin1_body<bf16>((const bf16*)x, (const bf16*)W1,
                                  (const bf16*)as1, (const bf16*)ad1, h1, als, ald);
}

// ---------------- CSR build: histogram, scan, scatter -------------------------
__global__ void k_hist(const void* ei, const int* __restrict__ flags,
                       int* __restrict__ counts) {
    int idx = blockIdx.x * blockDim.x + threadIdx.x;
    if (idx >= EN) return;
    int d = flags[1] ? dst_of<long long>((const long long*)ei, idx)
                     : dst_of<int>((const int*)ei, idx);
    atomicAdd(&counts[d], 1);
}

// one block, 1024 threads: exclusive scan of counts[0..NN) -> offsets, zero counts
__global__ void k_scan(int* __restrict__ counts, int* __restrict__ offsets) {
    __shared__ int ssum[1024];
    const int t = threadIdx.x;
    const int CH = (NN + 1023) / 1024;   // 49
    const int base = t * CH;
    int s = 0;
    for (int i = 0; i < CH; ++i) {
        int idx = base + i;
        if (idx < NN) s += counts[idx];
    }
    ssum[t] = s;
    __syncthreads();
    for (int off = 1; off < 1024; off <<= 1) {
        int v = (t >= off) ? ssum[t - off] : 0;
        __syncthreads();
        ssum[t] += v;
        __syncthreads();
    }
    int run = ssum[t] - s;   // exclusive prefix for this chunk
    for (int i = 0; i < CH; ++i) {
        int idx = base + i;
        if (idx < NN) {
            int c = counts[idx];
            offsets[idx] = run;
            run += c;
            counts[idx] = 0;   // becomes the scatter cursor
        }
    }
    if (t == 1023) offsets[NN] = ssum[1023];
}

__global__ void k_scatter(const void* ei, const int* __restrict__ flags,
                          const int* __restrict__ offsets, int* __restrict__ cursor,
                          int* __restrict__ eids) {
    int idx = blockIdx.x * blockDim.x + threadIdx.x;
    if (idx >= EN) return;
    int d = flags[1] ? dst_of<long long>((const long long*)ei, idx)
                     : dst_of<int>((const int*)ei, idx);
    int slot = offsets[d] + atomicAdd(&cursor[d], 1);
    eids[slot] = idx;
}

// ---------------- Layer 1 aggregate: gather, fused softmax, no atomics --------
__global__ void k_agg1(const void* ei, const int* __restrict__ flags,
                       const int* __restrict__ offsets, const int* __restrict__ eids,
                       const float* __restrict__ als, const float* __restrict__ ald,
                       const bf16* __restrict__ h1, float* __restrict__ out1) {
    const int d = blockIdx.x, t = threadIdx.x, h = t >> 5;
    const int start = offsets[d], end = offsets[d + 1];
    const int i64 = flags[1];
    const float adv = ald[d * 4 + h];
    float acc = 0.f, dsum = 0.f;
    __shared__ int ssrc[128];
    for (int c0 = start; c0 < end; c0 += 128) {
        int m = end - c0;
        if (m > 128) m = 128;
        __syncthreads();
        if (t < m) {
            int eid = eids[c0 + t];
            ssrc[t] = i64 ? src_of<long long>((const long long*)ei, eid)
                          : src_of<int>((const int*)ei, eid);
        }
        __syncthreads();
        for (int j = 0; j < m; ++j) {
            int s = ssrc[j];
            float ev = als[s * 4 + h] + adv;
            ev = ev > 0.f ? ev : NEG * ev;
            float ex = __expf(ev);
            acc += ex * cvt(h1[s * 128 + t]);
            dsum += ex;
        }
    }
    out1[d * 128 + t] = acc / (dsum + 1e-16f);
}

// ---------------- Mid: bias + ELU, h2 = h_mid @ W2, layer-2 logits ------------
template <typename T>
__device__ __forceinline__ void mid_body(const float* __restrict__ out1,
                                         const T* __restrict__ b1, const T* __restrict__ W2,
                                         const T* __restrict__ as2, const T* __restrict__ ad2,
                                         float* __restrict__ h2, float* __restrict__ als2,
                                         float* __restrict__ ald2) {
    __shared__ float hm[F1];
    __shared__ float part[F1];
    const int n = blockIdx.x, t = threadIdx.x;
    float v = out1[n * F1 + t] + cvt(b1[t]);
    hm[t] = v > 0.f ? v : (__expf(v) - 1.f);   // ELU(alpha=1)
    __syncthreads();
    const int j = t & 31, q = t >> 5;
    float p = 0.f;
#pragma unroll
    for (int kk = 0; kk < 32; ++kk) {
        int k = q * 32 + kk;
        p += hm[k] * cvt(W2[k * HID + j]);
    }
    part[t] = p;
    __syncthreads();
    if (t < 32) {
        float hv = part[t] + part[32 + t] + part[64 + t] + part[96 + t];
        h2[n * HID + t] = hv;
        float ps = hv * cvt(as2[t]);
        float pd = hv * cvt(ad2[t]);
#pragma unroll
        for (int off = 16; off > 0; off >>= 1) {
            ps += __shfl_down(ps, off, 32);
            pd += __shfl_down(pd, off, 32);
        }
        if (t == 0) { als2[n] = ps; ald2[n] = pd; }
    }
}

__global__ void k_mid(const float* out1, const void* b1, const void* W2,
                      const void* as2, const void* ad2, const int* __restrict__ flags,
                      float* h2, float* als2, float* ald2) {
    if (flags[0]) mid_body<float>(out1, (const float*)b1, (const float*)W2,
                                  (const float*)as2, (const float*)ad2, h2, als2, ald2);
    else          mid_body<bf16>(out1, (const bf16*)b1, (const bf16*)W2,
                                 (const bf16*)as2, (const bf16*)ad2, h2, als2, ald2);
}

// ---------------- Layer 2 aggregate + bias + store (8 nodes/block) ------------
__global__ void k_agg2(const void* ei, const int* __restrict__ flags,
                       const int* __restrict__ offsets, const int* __restrict__ eids,
                       const float* __restrict__ als2, const float* __restrict__ ald2,
                       const float* __restrict__ h2, const void* b2v, void* out) {
    const int t = threadIdx.x;
    const int node = blockIdx.x * 8 + (t >> 5);
    const int lane = t & 31;
    if (node >= NN) return;
    const int start = offsets[node], end = offsets[node + 1];
    const int i64 = flags[1];
    const float adv = ald2[node];
    float acc = 0.f, dsum = 0.f;
    for (int e = start; e < end; ++e) {
        int eid = eids[e];
        int s = i64 ? src_of<long long>((const long long*)ei, eid)
                    : src_of<int>((const int*)ei, eid);
        float ev = als2[s] + adv;
        ev = ev > 0.f ? ev : NEG * ev;
        float ex = __expf(ev);
        acc += ex * h2[s * 32 + lane];
        dsum += ex;
    }
    float r = acc / (dsum + 1e-16f);
    if (flags[0]) {
        ((float*)out)[node * 32 + lane] = r + ((const float*)b2v)[lane];
    } else {
        ((bf16*)out)[node * 32 + lane] =
            __float2bfloat16(r + cvt(((const bf16*)b2v)[lane]));
    }
}

extern "C" void kernel_launch(void* const* d_in, const int* in_sizes, int n_in,
                              void* d_out, int out_size, void* d_ws, size_t ws_size,
                              hipStream_t stream) {
    const void* x    = d_in[0];
    const void* ei   = d_in[1];
    const void* W1   = d_in[2];
    const void* a_s1 = d_in[3];
    const void* a_d1 = d_in[4];
    const void* b1   = d_in[5];
    const void* W2   = d_in[6];
    const void* a_s2 = d_in[7];
    const void* a_d2 = d_in[8];
    const void* b2v  = d_in[9];

    // ---- workspace layout (~44.2 MB) ----
    int*   flags  = (int*)d_ws;
    float* p      = (float*)d_ws + 64;
    float* out1   = p; p += (size_t)NN * F1;             // 25.6 MB
    bf16*  h1     = (bf16*)p; p += (size_t)NN * F1 / 2;  // 12.8 MB; reused as f32 h2
    float* h2     = (float*)h1;                          // alias (h1 dead after k_agg1)
    float* al_s1  = p; p += (size_t)NN * HEADS;
    float* al_d1  = p; p += (size_t)NN * HEADS;
    float* al_s2  = p; p += NN;
    float* al_d2  = p; p += NN;
    int*   offs   = (int*)p; p += NN + 1;
    int*   counts = (int*)p; p += NN;                    // doubles as scatter cursor
    int*   eids   = (int*)p; p += EN;                    // 3.4 MB

    hipMemsetAsync(counts, 0, (size_t)NN * sizeof(int), stream);

    k_detect<<<1, 64, 0, stream>>>((const unsigned*)x, (const unsigned*)ei, flags);
    k_hist<<<(EN + 255) / 256, 256, 0, stream>>>(ei, flags, counts);
    k_scan<<<1, 1024, 0, stream>>>(counts, offs);
    k_scatter<<<(EN + 255) / 256, 256, 0, stream>>>(ei, flags, offs, counts, eids);
    k_lin1<<<NN, 128, 0, stream>>>(x, W1, a_s1, a_d1, flags, h1, al_s1, al_d1);
    k_agg1<<<NN, 128, 0, stream>>>(ei, flags, offs, eids, al_s1, al_d1, h1, out1);
    k_mid<<<NN, 128, 0, stream>>>(out1, b1, W2, a_s2, a_d2, flags, h2, al_s2, al_d2);
    k_agg2<<<(NN + 7) / 8, 256, 0, stream>>>(ei, flags, offs, eids, al_s2, al_d2,
                                             h2, b2v, d_out);
}

// Round 5
// 395.577 us; speedup vs baseline: 2.3664x; 1.4519x over previous
//
#include <hip/hip_runtime.h>
#include <hip/hip_bf16.h>

#define NN 50000
#define EE 800000
#define EN (EE + NN)      // edges including self-loops
#define IN_DIM 128
#define HID 32
#define HEADS 4
#define F1 (HEADS * HID)  // 128
#define NEG 0.2f

typedef __hip_bfloat16 bf16;
typedef __bf16 bf16x8 __attribute__((ext_vector_type(8)));
typedef float f32x4 __attribute__((ext_vector_type(4)));

__device__ __forceinline__ float cvt(float v) { return v; }
__device__ __forceinline__ float cvt(bf16 v)  { return __bfloat162float(v); }

__device__ __forceinline__ unsigned short f2bf_bits(float f) {
    union { float f; unsigned u; } v; v.f = f;
    unsigned r = v.u + 0x7FFFu + ((v.u >> 16) & 1u);
    return (unsigned short)(r >> 16);
}

// ---------------- dtype detector: flags[0]=float-is-f32, flags[1]=edge-is-i64 --
__global__ void k_detect(const unsigned* __restrict__ xw, const unsigned* __restrict__ ew,
                         int* __restrict__ flags) {
    if (threadIdx.x == 0 && blockIdx.x == 0) {
        int all_lo_zero = 1, huge = 0;
        for (int i = 0; i < 256; ++i) {
            unsigned lo = xw[i] & 0xFFFFu;
            if (lo != 0u) all_lo_zero = 0;
            unsigned ex = (lo >> 7) & 0xFFu;
            if (ex >= 0xC0u) huge = 1;
        }
        flags[0] = (all_lo_zero || huge) ? 1 : 0;
        int i64 = 1;
        for (int i = 1; i < 256; i += 2) if (ew[i] != 0u) i64 = 0;
        flags[1] = i64;
    }
}

// ---------------- edge decode helpers ----------------------------------------
template <typename IT>
__device__ __forceinline__ int dst_of(const IT* __restrict__ ei, int idx) {
    return idx < EE ? (int)ei[EE + idx] : idx - EE;
}
template <typename IT>
__device__ __forceinline__ int src_of(const IT* __restrict__ ei, int eid) {
    return eid < EE ? (int)ei[eid] : eid - EE;
}

// ---------------- Layer 1 linear via MFMA: h1(bf16) = x @ W1, + logits --------
#define MROWS 64
#define LDK 136   // padded LDS row stride (elements) -> 272 B, 16B-aligned frags

__global__ __launch_bounds__(256) void k_lin1_mfma(
    const void* xv, const void* W1v, const void* as1v, const void* ad1v,
    const int* __restrict__ flags, bf16* __restrict__ h1,
    float* __restrict__ als, float* __restrict__ ald)
{
    __shared__ __align__(16) char smem[(MROWS + 128) * LDK * 2];  // 52,224 B
    unsigned short* xs  = (unsigned short*)smem;       // [MROWS][LDK] bf16 bits
    unsigned short* w1t = xs + MROWS * LDK;            // [128][LDK]   (n-major)
    float* hs = (float*)smem;                          // phase2 alias: [MROWS][132]
    __shared__ float sa[F1], sd[F1];

    const int t = threadIdx.x;
    const int row0 = blockIdx.x * MROWS;
    const int f32in = flags[0];

    if (t < F1) {
        sa[t] = f32in ? ((const float*)as1v)[t] : cvt(((const bf16*)as1v)[t]);
        sd[t] = f32in ? ((const float*)ad1v)[t] : cvt(((const bf16*)ad1v)[t]);
    }
    if (!f32in) {
        const uint4* xg = (const uint4*)xv;            // 16 B = 8 bf16
        for (int i = 0; i < 4; ++i) {
            int id = i * 256 + t;                      // 0..1023
            int m = id >> 4, seg = id & 15;
            int gr = row0 + m;
            uint4 val = (gr < NN) ? xg[(size_t)gr * 16 + seg] : make_uint4(0, 0, 0, 0);
            *(uint4*)&xs[m * LDK + seg * 8] = val;
        }
        const unsigned short* wg = (const unsigned short*)W1v;
        for (int i = 0; i < 64; ++i) {
            int id = i * 256 + t;                      // 0..16383
            int k = id >> 7, n = id & 127;
            w1t[n * LDK + k] = wg[id];
        }
    } else {
        const float* xf = (const float*)xv;
        for (int i = 0; i < 32; ++i) {
            int id = i * 256 + t;
            int m = id >> 7, c = id & 127;
            int gr = row0 + m;
            xs[m * LDK + c] = (gr < NN) ? f2bf_bits(xf[(size_t)gr * 128 + c]) : 0;
        }
        const float* wf = (const float*)W1v;
        for (int i = 0; i < 64; ++i) {
            int id = i * 256 + t;
            int k = id >> 7, n = id & 127;
            w1t[n * LDK + k] = f2bf_bits(wf[id]);
        }
    }
    __syncthreads();

    const int wave = t >> 6, lane = t & 63, quad = lane >> 4, l16 = lane & 15;
    f32x4 acc[8];
#pragma unroll
    for (int ni = 0; ni < 8; ++ni) acc[ni] = (f32x4){0.f, 0.f, 0.f, 0.f};

    const int arow = wave * 16 + l16;
#pragma unroll
    for (int kc = 0; kc < 4; ++kc) {
        int ko = kc * 32 + quad * 8;
        bf16x8 av = *(const bf16x8*)&xs[arow * LDK + ko];
#pragma unroll
        for (int ni = 0; ni < 8; ++ni) {
            bf16x8 bv = *(const bf16x8*)&w1t[(ni * 16 + l16) * LDK + ko];
            acc[ni] = __builtin_amdgcn_mfma_f32_16x16x32_bf16(av, bv, acc[ni], 0, 0, 0);
        }
    }
    __syncthreads();   // staging LDS dead; reuse as hs

#pragma unroll
    for (int ni = 0; ni < 8; ++ni)
#pragma unroll
        for (int r = 0; r < 4; ++r) {
            int m = wave * 16 + quad * 4 + r;          // C/D: row=quad*4+reg, col=l16
            hs[m * 132 + ni * 16 + l16] = acc[ni][r];
        }
    __syncthreads();

    for (int i = 0; i < 32; ++i) {
        int id = i * 256 + t;                          // 0..8191
        int m = id >> 7, c = id & 127;
        int gr = row0 + m;
        if (gr < NN)
            h1[(size_t)gr * 128 + c] = __float2bfloat16(hs[m * 132 + c]);
    }
    {
        int m = t >> 2, h = t & 3;                     // 64 nodes x 4 heads
        int gr = row0 + m;
        if (gr < NN) {
            float ps = 0.f, pd = 0.f;
#pragma unroll
            for (int j = 0; j < 32; ++j) {
                float v = hs[m * 132 + h * 32 + j];
                ps += v * sa[h * 32 + j];
                pd += v * sd[h * 32 + j];
            }
            als[gr * 4 + h] = ps;
            ald[gr * 4 + h] = pd;
        }
    }
}

// ---------------- CSR build: histogram + 3-phase multi-block scan + scatter ---
#define SCAN_B 196   // ceil(NN/256)

__global__ void k_hist(const void* ei, const int* __restrict__ flags,
                       int* __restrict__ counts) {
    int idx = blockIdx.x * blockDim.x + threadIdx.x;
    if (idx >= EN) return;
    int d = flags[1] ? dst_of<long long>((const long long*)ei, idx)
                     : dst_of<int>((const int*)ei, idx);
    atomicAdd(&counts[d], 1);
}

__global__ void k_scanA(const int* __restrict__ counts, int* __restrict__ bsum) {
    __shared__ int sh[256];
    int i = blockIdx.x * 256 + threadIdx.x;
    sh[threadIdx.x] = (i < NN) ? counts[i] : 0;
    __syncthreads();
    for (int off = 128; off > 0; off >>= 1) {
        if (threadIdx.x < off) sh[threadIdx.x] += sh[threadIdx.x + off];
        __syncthreads();
    }
    if (threadIdx.x == 0) bsum[blockIdx.x] = sh[0];
}

__global__ void k_scanB(const int* __restrict__ bsum, int* __restrict__ bbase) {
    __shared__ int sh[256];
    int t = threadIdx.x;
    int v = (t < SCAN_B) ? bsum[t] : 0;
    sh[t] = v;
    __syncthreads();
    for (int off = 1; off < 256; off <<= 1) {
        int u = (t >= off) ? sh[t - off] : 0;
        __syncthreads();
        sh[t] += u;
        __syncthreads();
    }
    if (t < SCAN_B) bbase[t] = sh[t] - v;   // exclusive prefix of block sums
}

__global__ void k_scanC(int* __restrict__ counts, const int* __restrict__ bbase,
                        int* __restrict__ offsets) {
    __shared__ int sh[256];
    int t = threadIdx.x;
    int i = blockIdx.x * 256 + t;
    int v = (i < NN) ? counts[i] : 0;
    sh[t] = v;
    __syncthreads();
    for (int off = 1; off < 256; off <<= 1) {
        int u = (t >= off) ? sh[t - off] : 0;
        __syncthreads();
        sh[t] += u;
        __syncthreads();
    }
    if (i < NN) {
        offsets[i] = bbase[blockIdx.x] + sh[t] - v;
        counts[i] = 0;                       // becomes the scatter cursor
    } else if (i == NN) {
        offsets[NN] = EN;                    // total is static
    }
}

__global__ void k_scatter(const void* ei, const int* __restrict__ flags,
                          const int* __restrict__ offsets, int* __restrict__ cursor,
                          int* __restrict__ eids) {
    int idx = blockIdx.x * blockDim.x + threadIdx.x;
    if (idx >= EN) return;
    int d = flags[1] ? dst_of<long long>((const long long*)ei, idx)
                     : dst_of<int>((const int*)ei, idx);
    int slot = offsets[d] + atomicAdd(&cursor[d], 1);
    eids[slot] = idx;
}

// ---------------- Layer 1 aggregate: gather, fused softmax, no atomics --------
__global__ void k_agg1(const void* ei, const int* __restrict__ flags,
                       const int* __restrict__ offsets, const int* __restrict__ eids,
                       const float* __restrict__ als, const float* __restrict__ ald,
                       const bf16* __restrict__ h1, float* __restrict__ out1) {
    const int d = blockIdx.x, t = threadIdx.x, h = t >> 5;
    const int start = offsets[d], end = offsets[d + 1];
    const int i64 = flags[1];
    const float adv = ald[d * 4 + h];
    float acc = 0.f, dsum = 0.f;
    __shared__ int ssrc[128];
    for (int c0 = start; c0 < end; c0 += 128) {
        int m = end - c0;
        if (m > 128) m = 128;
        __syncthreads();
        if (t < m) {
            int eid = eids[c0 + t];
            ssrc[t] = i64 ? src_of<long long>((const long long*)ei, eid)
                          : src_of<int>((const int*)ei, eid);
        }
        __syncthreads();
        for (int j = 0; j < m; ++j) {
            int s = ssrc[j];
            float ev = als[s * 4 + h] + adv;
            ev = ev > 0.f ? ev : NEG * ev;
            float ex = __expf(ev);
            acc += ex * cvt(h1[s * 128 + t]);
            dsum += ex;
        }
    }
    out1[d * 128 + t] = acc / (dsum + 1e-16f);
}

// ---------------- Mid: bias + ELU, h2 = h_mid @ W2, layer-2 logits ------------
template <typename T>
__device__ __forceinline__ void mid_body(const float* __restrict__ out1,
                                         const T* __restrict__ b1, const T* __restrict__ W2,
                                         const T* __restrict__ as2, const T* __restrict__ ad2,
                                         float* __restrict__ h2, float* __restrict__ als2,
                                         float* __restrict__ ald2) {
    __shared__ float hm[F1];
    __shared__ float part[F1];
    const int n = blockIdx.x, t = threadIdx.x;
    float v = out1[n * F1 + t] + cvt(b1[t]);
    hm[t] = v > 0.f ? v : (__expf(v) - 1.f);   // ELU(alpha=1)
    __syncthreads();
    const int j = t & 31, q = t >> 5;
    float p = 0.f;
#pragma unroll
    for (int kk = 0; kk < 32; ++kk) {
        int k = q * 32 + kk;
        p += hm[k] * cvt(W2[k * HID + j]);
    }
    part[t] = p;
    __syncthreads();
    if (t < 32) {
        float hv = part[t] + part[32 + t] + part[64 + t] + part[96 + t];
        h2[n * HID + t] = hv;
        float ps = hv * cvt(as2[t]);
        float pd = hv * cvt(ad2[t]);
#pragma unroll
        for (int off = 16; off > 0; off >>= 1) {
            ps += __shfl_down(ps, off, 32);
            pd += __shfl_down(pd, off, 32);
        }
        if (t == 0) { als2[n] = ps; ald2[n] = pd; }
    }
}

__global__ void k_mid(const float* out1, const void* b1, const void* W2,
                      const void* as2, const void* ad2, const int* __restrict__ flags,
                      float* h2, float* als2, float* ald2) {
    if (flags[0]) mid_body<float>(out1, (const float*)b1, (const float*)W2,
                                  (const float*)as2, (const float*)ad2, h2, als2, ald2);
    else          mid_body<bf16>(out1, (const bf16*)b1, (const bf16*)W2,
                                 (const bf16*)as2, (const bf16*)ad2, h2, als2, ald2);
}

// ---------------- Layer 2 aggregate + bias + store (8 nodes/block) ------------
__global__ void k_agg2(const void* ei, const int* __restrict__ flags,
                       const int* __restrict__ offsets, const int* __restrict__ eids,
                       const float* __restrict__ als2, const float* __restrict__ ald2,
                       const float* __restrict__ h2, const void* b2v, void* out) {
    const int t = threadIdx.x;
    const int node = blockIdx.x * 8 + (t >> 5);
    const int lane = t & 31;
    if (node >= NN) return;
    const int start = offsets[node], end = offsets[node + 1];
    const int i64 = flags[1];
    const float adv = ald2[node];
    float acc = 0.f, dsum = 0.f;
    for (int e = start; e < end; ++e) {
        int eid = eids[e];
        int s = i64 ? src_of<long long>((const long long*)ei, eid)
                    : src_of<int>((const int*)ei, eid);
        float ev = als2[s] + adv;
        ev = ev > 0.f ? ev : NEG * ev;
        float ex = __expf(ev);
        acc += ex * h2[s * 32 + lane];
        dsum += ex;
    }
    float r = acc / (dsum + 1e-16f);
    if (flags[0]) {
        ((float*)out)[node * 32 + lane] = r + ((const float*)b2v)[lane];
    } else {
        ((bf16*)out)[node * 32 + lane] =
            __float2bfloat16(r + cvt(((const bf16*)b2v)[lane]));
    }
}

extern "C" void kernel_launch(void* const* d_in, const int* in_sizes, int n_in,
                              void* d_out, int out_size, void* d_ws, size_t ws_size,
                              hipStream_t stream) {
    const void* x    = d_in[0];
    const void* ei   = d_in[1];
    const void* W1   = d_in[2];
    const void* a_s1 = d_in[3];
    const void* a_d1 = d_in[4];
    const void* b1   = d_in[5];
    const void* W2   = d_in[6];
    const void* a_s2 = d_in[7];
    const void* a_d2 = d_in[8];
    const void* b2v  = d_in[9];

    // ---- workspace layout (~44.2 MB) ----
    int*   flags  = (int*)d_ws;
    float* p      = (float*)d_ws + 64;
    float* out1   = p; p += (size_t)NN * F1;             // 25.6 MB
    bf16*  h1     = (bf16*)p; p += (size_t)NN * F1 / 2;  // 12.8 MB; reused as f32 h2
    float* h2     = (float*)h1;                          // alias (h1 dead after k_agg1)
    float* al_s1  = p; p += (size_t)NN * HEADS;
    float* al_d1  = p; p += (size_t)NN * HEADS;
    float* al_s2  = p; p += NN;
    float* al_d2  = p; p += NN;
    int*   offs   = (int*)p; p += NN + 1;
    int*   counts = (int*)p; p += NN;                    // doubles as scatter cursor
    int*   eids   = (int*)p; p += EN;                    // 3.4 MB
    int*   bsum   = (int*)p; p += SCAN_B;
    int*   bbase  = (int*)p; p += SCAN_B;

    hipMemsetAsync(counts, 0, (size_t)NN * sizeof(int), stream);

    k_detect<<<1, 64, 0, stream>>>((const unsigned*)x, (const unsigned*)ei, flags);
    k_hist<<<(EN + 255) / 256, 256, 0, stream>>>(ei, flags, counts);
    k_scanA<<<SCAN_B, 256, 0, stream>>>(counts, bsum);
    k_scanB<<<1, 256, 0, stream>>>(bsum, bbase);
    k_scanC<<<SCAN_B, 256, 0, stream>>>(counts, bbase, offs);
    k_scatter<<<(EN + 255) / 256, 256, 0, stream>>>(ei, flags, offs, counts, eids);
    k_lin1_mfma<<<(NN + MROWS - 1) / MROWS, 256, 0, stream>>>(x, W1, a_s1, a_d1,
                                                              flags, h1, al_s1, al_d1);
    k_agg1<<<NN, 128, 0, stream>>>(ei, flags, offs, eids, al_s1, al_d1, h1, out1);
    k_mid<<<NN, 128, 0, stream>>>(out1, b1, W2, a_s2, a_d2, flags, h2, al_s2, al_d2);
    k_agg2<<<(NN + 7) / 8, 256, 0, stream>>>(ei, flags, offs, eids, al_s2, al_d2,
                                             h2, b2v, d_out);
}

// Round 6
// 366.987 us; speedup vs baseline: 2.5508x; 1.0779x over previous
//
#include <hip/hip_runtime.h>
#include <hip/hip_bf16.h>

#define NN 50000
#define EE 800000
#define EN (EE + NN)      // edges including self-loops
#define IN_DIM 128
#define HID 32
#define HEADS 4
#define F1 (HEADS * HID)  // 128
#define NEG 0.2f

typedef __hip_bfloat16 bf16;
typedef __bf16 bf16x8 __attribute__((ext_vector_type(8)));
typedef float f32x4 __attribute__((ext_vector_type(4)));

__device__ __forceinline__ float cvt(float v) { return v; }
__device__ __forceinline__ float cvt(bf16 v)  { return __bfloat162float(v); }

__device__ __forceinline__ float bflo(unsigned u) {
    union { unsigned u; float f; } v; v.u = u << 16; return v.f;
}
__device__ __forceinline__ float bfhi(unsigned u) {
    union { unsigned u; float f; } v; v.u = u & 0xFFFF0000u; return v.f;
}

__device__ __forceinline__ unsigned short f2bf_bits(float f) {
    union { float f; unsigned u; } v; v.f = f;
    unsigned r = v.u + 0x7FFFu + ((v.u >> 16) & 1u);
    return (unsigned short)(r >> 16);
}

// ---------------- dtype detector: flags[0]=float-is-f32, flags[1]=edge-is-i64 --
__global__ void k_detect(const unsigned* __restrict__ xw, const unsigned* __restrict__ ew,
                         int* __restrict__ flags) {
    if (threadIdx.x == 0 && blockIdx.x == 0) {
        int all_lo_zero = 1, huge = 0;
        for (int i = 0; i < 256; ++i) {
            unsigned lo = xw[i] & 0xFFFFu;
            if (lo != 0u) all_lo_zero = 0;
            unsigned ex = (lo >> 7) & 0xFFu;
            if (ex >= 0xC0u) huge = 1;
        }
        flags[0] = (all_lo_zero || huge) ? 1 : 0;
        int i64 = 1;
        for (int i = 1; i < 256; i += 2) if (ew[i] != 0u) i64 = 0;
        flags[1] = i64;
    }
}

// ---------------- edge decode helpers ----------------------------------------
template <typename IT>
__device__ __forceinline__ void get_sd(const IT* __restrict__ ei, int idx, int& s, int& d) {
    if (idx < EE) { s = (int)ei[idx]; d = (int)ei[EE + idx]; }
    else          { s = d = idx - EE; }
}
template <typename IT>
__device__ __forceinline__ int dst_of(const IT* __restrict__ ei, int idx) {
    return idx < EE ? (int)ei[EE + idx] : idx - EE;
}

// ---------------- Layer 1 linear via MFMA: h1(bf16) = x @ W1, + logits --------
#define MROWS 64
#define LDK 136   // padded LDS row stride (elements) -> 272 B, 16B-aligned frags

__global__ __launch_bounds__(256) void k_lin1_mfma(
    const void* xv, const void* W1v, const void* as1v, const void* ad1v,
    const int* __restrict__ flags, bf16* __restrict__ h1,
    float* __restrict__ als, float* __restrict__ ald)
{
    __shared__ __align__(16) char smem[(MROWS + 128) * LDK * 2];  // 52,224 B
    unsigned short* xs  = (unsigned short*)smem;       // [MROWS][LDK] bf16 bits
    unsigned short* w1t = xs + MROWS * LDK;            // [128][LDK]   (n-major)
    float* hs = (float*)smem;                          // phase2 alias: [MROWS][132]
    __shared__ float sa[F1], sd[F1];

    const int t = threadIdx.x;
    const int row0 = blockIdx.x * MROWS;
    const int f32in = flags[0];

    if (t < F1) {
        sa[t] = f32in ? ((const float*)as1v)[t] : cvt(((const bf16*)as1v)[t]);
        sd[t] = f32in ? ((const float*)ad1v)[t] : cvt(((const bf16*)ad1v)[t]);
    }
    if (!f32in) {
        const uint4* xg = (const uint4*)xv;            // 16 B = 8 bf16
        for (int i = 0; i < 4; ++i) {
            int id = i * 256 + t;                      // 0..1023
            int m = id >> 4, seg = id & 15;
            int gr = row0 + m;
            uint4 val = (gr < NN) ? xg[(size_t)gr * 16 + seg] : make_uint4(0, 0, 0, 0);
            *(uint4*)&xs[m * LDK + seg * 8] = val;
        }
        const unsigned short* wg = (const unsigned short*)W1v;
        for (int i = 0; i < 64; ++i) {
            int id = i * 256 + t;                      // 0..16383
            int k = id >> 7, n = id & 127;
            w1t[n * LDK + k] = wg[id];
        }
    } else {
        const float* xf = (const float*)xv;
        for (int i = 0; i < 32; ++i) {
            int id = i * 256 + t;
            int m = id >> 7, c = id & 127;
            int gr = row0 + m;
            xs[m * LDK + c] = (gr < NN) ? f2bf_bits(xf[(size_t)gr * 128 + c]) : 0;
        }
        const float* wf = (const float*)W1v;
        for (int i = 0; i < 64; ++i) {
            int id = i * 256 + t;
            int k = id >> 7, n = id & 127;
            w1t[n * LDK + k] = f2bf_bits(wf[id]);
        }
    }
    __syncthreads();

    const int wave = t >> 6, lane = t & 63, quad = lane >> 4, l16 = lane & 15;
    f32x4 acc[8];
#pragma unroll
    for (int ni = 0; ni < 8; ++ni) acc[ni] = (f32x4){0.f, 0.f, 0.f, 0.f};

    const int arow = wave * 16 + l16;
#pragma unroll
    for (int kc = 0; kc < 4; ++kc) {
        int ko = kc * 32 + quad * 8;
        bf16x8 av = *(const bf16x8*)&xs[arow * LDK + ko];
#pragma unroll
        for (int ni = 0; ni < 8; ++ni) {
            bf16x8 bv = *(const bf16x8*)&w1t[(ni * 16 + l16) * LDK + ko];
            acc[ni] = __builtin_amdgcn_mfma_f32_16x16x32_bf16(av, bv, acc[ni], 0, 0, 0);
        }
    }
    __syncthreads();   // staging LDS dead; reuse as hs

#pragma unroll
    for (int ni = 0; ni < 8; ++ni)
#pragma unroll
        for (int r = 0; r < 4; ++r) {
            int m = wave * 16 + quad * 4 + r;          // C/D: row=quad*4+reg, col=l16
            hs[m * 132 + ni * 16 + l16] = acc[ni][r];
        }
    __syncthreads();

    for (int i = 0; i < 32; ++i) {
        int id = i * 256 + t;                          // 0..8191
        int m = id >> 7, c = id & 127;
        int gr = row0 + m;
        if (gr < NN)
            h1[(size_t)gr * 128 + c] = __float2bfloat16(hs[m * 132 + c]);
    }
    {
        int m = t >> 2, h = t & 3;                     // 64 nodes x 4 heads
        int gr = row0 + m;
        if (gr < NN) {
            float ps = 0.f, pd = 0.f;
#pragma unroll
            for (int j = 0; j < 32; ++j) {
                float v = hs[m * 132 + h * 32 + j];
                ps += v * sa[h * 32 + j];
                pd += v * sd[h * 32 + j];
            }
            als[gr * 4 + h] = ps;
            ald[gr * 4 + h] = pd;
        }
    }
}

// ---------------- CSR build: histogram + 3-phase multi-block scan + scatter ---
#define SCAN_B 196   // ceil(NN/256)

__global__ void k_hist(const void* ei, const int* __restrict__ flags,
                       int* __restrict__ counts) {
    int idx = blockIdx.x * blockDim.x + threadIdx.x;
    if (idx >= EN) return;
    int d = flags[1] ? dst_of<long long>((const long long*)ei, idx)
                     : dst_of<int>((const int*)ei, idx);
    atomicAdd(&counts[d], 1);
}

__global__ void k_scanA(const int* __restrict__ counts, int* __restrict__ bsum) {
    __shared__ int sh[256];
    int i = blockIdx.x * 256 + threadIdx.x;
    sh[threadIdx.x] = (i < NN) ? counts[i] : 0;
    __syncthreads();
    for (int off = 128; off > 0; off >>= 1) {
        if (threadIdx.x < off) sh[threadIdx.x] += sh[threadIdx.x + off];
        __syncthreads();
    }
    if (threadIdx.x == 0) bsum[blockIdx.x] = sh[0];
}

__global__ void k_scanB(const int* __restrict__ bsum, int* __restrict__ bbase) {
    __shared__ int sh[256];
    int t = threadIdx.x;
    int v = (t < SCAN_B) ? bsum[t] : 0;
    sh[t] = v;
    __syncthreads();
    for (int off = 1; off < 256; off <<= 1) {
        int u = (t >= off) ? sh[t - off] : 0;
        __syncthreads();
        sh[t] += u;
        __syncthreads();
    }
    if (t < SCAN_B) bbase[t] = sh[t] - v;   // exclusive prefix of block sums
}

__global__ void k_scanC(int* __restrict__ counts, const int* __restrict__ bbase,
                        int* __restrict__ offsets) {
    __shared__ int sh[256];
    int t = threadIdx.x;
    int i = blockIdx.x * 256 + t;
    int v = (i < NN) ? counts[i] : 0;
    sh[t] = v;
    __syncthreads();
    for (int off = 1; off < 256; off <<= 1) {
        int u = (t >= off) ? sh[t - off] : 0;
        __syncthreads();
        sh[t] += u;
        __syncthreads();
    }
    if (i < NN) {
        offsets[i] = bbase[blockIdx.x] + sh[t] - v;
        counts[i] = 0;                       // becomes the scatter cursor
    } else if (i == NN) {
        offsets[NN] = EN;                    // total is static
    }
}

// scatter SOURCE node ids (not edge ids) into CSR order -> no 2nd indirection later
__global__ void k_scatter(const void* ei, const int* __restrict__ flags,
                          const int* __restrict__ offsets, int* __restrict__ cursor,
                          int* __restrict__ srcs) {
    int idx = blockIdx.x * blockDim.x + threadIdx.x;
    if (idx >= EN) return;
    int s, d;
    if (flags[1]) get_sd<long long>((const long long*)ei, idx, s, d);
    else          get_sd<int>((const int*)ei, idx, s, d);
    int slot = offsets[d] + atomicAdd(&cursor[d], 1);
    srcs[slot] = s;
}

// ---------------- Layer 1 aggregate: 1 wave/node, 2 ch/lane, unroll x2 --------
__global__ __launch_bounds__(256) void k_agg1(
    const int* __restrict__ offsets, const int* __restrict__ srcs,
    const float* __restrict__ als, const float* __restrict__ ald,
    const bf16* __restrict__ h1, float* __restrict__ out1)
{
    const int lane = threadIdx.x & 63;
    const int d = blockIdx.x * 4 + (threadIdx.x >> 6);
    const int h = lane >> 4;                 // head of this lane's 2 channels
    const int start = offsets[d], end = offsets[d + 1];
    const float adv = ald[d * 4 + h];
    const unsigned* h1u = (const unsigned*)h1;   // 2 bf16 per word

    float a0 = 0.f, a1 = 0.f, ds0 = 0.f;
    float b0 = 0.f, b1 = 0.f, ds1 = 0.f;
    int e = start;
    for (; e + 1 < end; e += 2) {
        int s0 = srcs[e], s1 = srcs[e + 1];
        float ev0 = als[s0 * 4 + h] + adv;
        float ev1 = als[s1 * 4 + h] + adv;
        ev0 = ev0 > 0.f ? ev0 : NEG * ev0;
        ev1 = ev1 > 0.f ? ev1 : NEG * ev1;
        float ex0 = __expf(ev0), ex1 = __expf(ev1);
        unsigned u0 = h1u[s0 * 64 + lane];
        unsigned u1 = h1u[s1 * 64 + lane];
        a0 += ex0 * bflo(u0); a1 += ex0 * bfhi(u0); ds0 += ex0;
        b0 += ex1 * bflo(u1); b1 += ex1 * bfhi(u1); ds1 += ex1;
    }
    if (e < end) {
        int s0 = srcs[e];
        float ev0 = als[s0 * 4 + h] + adv;
        ev0 = ev0 > 0.f ? ev0 : NEG * ev0;
        float ex0 = __expf(ev0);
        unsigned u0 = h1u[s0 * 64 + lane];
        a0 += ex0 * bflo(u0); a1 += ex0 * bfhi(u0); ds0 += ex0;
    }
    float inv = 1.f / (ds0 + ds1 + 1e-16f);
    float2 r = make_float2((a0 + b0) * inv, (a1 + b1) * inv);
    *(float2*)&out1[(size_t)d * 128 + lane * 2] = r;
}

// ---------------- Mid: bias + ELU, h2 = h_mid @ W2, layer-2 logits ------------
template <typename T>
__device__ __forceinline__ void mid_body(const float* __restrict__ out1,
                                         const T* __restrict__ b1, const T* __restrict__ W2,
                                         const T* __restrict__ as2, const T* __restrict__ ad2,
                                         float* __restrict__ h2, float* __restrict__ als2,
                                         float* __restrict__ ald2) {
    __shared__ float hm[F1];
    __shared__ float part[F1];
    const int n = blockIdx.x, t = threadIdx.x;
    float v = out1[n * F1 + t] + cvt(b1[t]);
    hm[t] = v > 0.f ? v : (__expf(v) - 1.f);   // ELU(alpha=1)
    __syncthreads();
    const int j = t & 31, q = t >> 5;
    float p = 0.f;
#pragma unroll
    for (int kk = 0; kk < 32; ++kk) {
        int k = q * 32 + kk;
        p += hm[k] * cvt(W2[k * HID + j]);
    }
    part[t] = p;
    __syncthreads();
    if (t < 32) {
        float hv = part[t] + part[32 + t] + part[64 + t] + part[96 + t];
        h2[n * HID + t] = hv;
        float ps = hv * cvt(as2[t]);
        float pd = hv * cvt(ad2[t]);
#pragma unroll
        for (int off = 16; off > 0; off >>= 1) {
            ps += __shfl_down(ps, off, 32);
            pd += __shfl_down(pd, off, 32);
        }
        if (t == 0) { als2[n] = ps; ald2[n] = pd; }
    }
}

__global__ void k_mid(const float* out1, const void* b1, const void* W2,
                      const void* as2, const void* ad2, const int* __restrict__ flags,
                      float* h2, float* als2, float* ald2) {
    if (flags[0]) mid_body<float>(out1, (const float*)b1, (const float*)W2,
                                  (const float*)as2, (const float*)ad2, h2, als2, ald2);
    else          mid_body<bf16>(out1, (const bf16*)b1, (const bf16*)W2,
                                 (const bf16*)as2, (const bf16*)ad2, h2, als2, ald2);
}

// ---------------- Layer 2 aggregate: 1 wave/node, halves take even/odd edges --
__global__ __launch_bounds__(256) void k_agg2(
    const int* __restrict__ offsets, const int* __restrict__ srcs,
    const float* __restrict__ als2, const float* __restrict__ ald2,
    const float* __restrict__ h2, const void* b2v, const int* __restrict__ flags,
    void* out)
{
    const int lane = threadIdx.x & 63;
    const int node = blockIdx.x * 4 + (threadIdx.x >> 6);
    const int q = lane >> 5, c = lane & 31;
    const int start = offsets[node], end = offsets[node + 1];
    const float adv = ald2[node];

    float acc = 0.f, dsum = 0.f;
    for (int e = start + q; e < end; e += 2) {
        int s = srcs[e];
        float ev = als2[s] + adv;
        ev = ev > 0.f ? ev : NEG * ev;
        float ex = __expf(ev);
        acc += ex * h2[s * 32 + c];
        dsum += ex;
    }
    acc  += __shfl_xor(acc, 32);
    dsum += __shfl_xor(dsum, 32);
    if (q == 0) {
        float r = acc / (dsum + 1e-16f);
        if (flags[0]) {
            ((float*)out)[node * 32 + c] = r + ((const float*)b2v)[c];
        } else {
            ((bf16*)out)[node * 32 + c] =
                __float2bfloat16(r + cvt(((const bf16*)b2v)[c]));
        }
    }
}

extern "C" void kernel_launch(void* const* d_in, const int* in_sizes, int n_in,
                              void* d_out, int out_size, void* d_ws, size_t ws_size,
                              hipStream_t stream) {
    const void* x    = d_in[0];
    const void* ei   = d_in[1];
    const void* W1   = d_in[2];
    const void* a_s1 = d_in[3];
    const void* a_d1 = d_in[4];
    const void* b1   = d_in[5];
    const void* W2   = d_in[6];
    const void* a_s2 = d_in[7];
    const void* a_d2 = d_in[8];
    const void* b2v  = d_in[9];

    // ---- workspace layout (~44.2 MB) ----
    int*   flags  = (int*)d_ws;
    float* p      = (float*)d_ws + 64;
    float* out1   = p; p += (size_t)NN * F1;             // 25.6 MB
    bf16*  h1     = (bf16*)p; p += (size_t)NN * F1 / 2;  // 12.8 MB; reused as f32 h2
    float* h2     = (float*)h1;                          // alias (h1 dead after k_agg1)
    float* al_s1  = p; p += (size_t)NN * HEADS;
    float* al_d1  = p; p += (size_t)NN * HEADS;
    float* al_s2  = p; p += NN;
    float* al_d2  = p; p += NN;
    int*   offs   = (int*)p; p += NN + 1;
    int*   counts = (int*)p; p += NN;                    // doubles as scatter cursor
    int*   srcs   = (int*)p; p += EN;                    // 3.4 MB (CSR source ids)
    int*   bsum   = (int*)p; p += SCAN_B;
    int*   bbase  = (int*)p; p += SCAN_B;

    hipMemsetAsync(counts, 0, (size_t)NN * sizeof(int), stream);

    k_detect<<<1, 64, 0, stream>>>((const unsigned*)x, (const unsigned*)ei, flags);
    k_hist<<<(EN + 255) / 256, 256, 0, stream>>>(ei, flags, counts);
    k_scanA<<<SCAN_B, 256, 0, stream>>>(counts, bsum);
    k_scanB<<<1, 256, 0, stream>>>(bsum, bbase);
    k_scanC<<<SCAN_B, 256, 0, stream>>>(counts, bbase, offs);
    k_scatter<<<(EN + 255) / 256, 256, 0, stream>>>(ei, flags, offs, counts, srcs);
    k_lin1_mfma<<<(NN + MROWS - 1) / MROWS, 256, 0, stream>>>(x, W1, a_s1, a_d1,
                                                              flags, h1, al_s1, al_d1);
    k_agg1<<<NN / 4, 256, 0, stream>>>(offs, srcs, al_s1, al_d1, h1, out1);
    k_mid<<<NN, 128, 0, stream>>>(out1, b1, W2, a_s2, a_d2, flags, h2, al_s2, al_d2);
    k_agg2<<<NN / 4, 256, 0, stream>>>(offs, srcs, al_s2, al_d2, h2, b2v, flags, d_out);
}

// Round 7
// 306.612 us; speedup vs baseline: 3.0531x; 1.1969x over previous
//
#include <hip/hip_runtime.h>
#include <hip/hip_bf16.h>

#define NN 50000
#define EE 800000
#define EN (EE + NN)      // edges including self-loops
#define IN_DIM 128
#define HID 32
#define HEADS 4
#define F1 (HEADS * HID)  // 128
#define NEG 0.2f

typedef __hip_bfloat16 bf16;
typedef __bf16 bf16x8 __attribute__((ext_vector_type(8)));
typedef float f32x4 __attribute__((ext_vector_type(4)));

__device__ __forceinline__ float cvt(float v) { return v; }
__device__ __forceinline__ float cvt(bf16 v)  { return __bfloat162float(v); }

__device__ __forceinline__ float bflo(unsigned u) {
    union { unsigned u; float f; } v; v.u = u << 16; return v.f;
}
__device__ __forceinline__ float bfhi(unsigned u) {
    union { unsigned u; float f; } v; v.u = u & 0xFFFF0000u; return v.f;
}

__device__ __forceinline__ unsigned short f2bf_bits(float f) {
    union { float f; unsigned u; } v; v.f = f;
    unsigned r = v.u + 0x7FFFu + ((v.u >> 16) & 1u);
    return (unsigned short)(r >> 16);
}

// ---------------- dtype detector: flags[0]=float-is-f32, flags[1]=edge-is-i64 --
__global__ void k_detect(const unsigned* __restrict__ xw, const unsigned* __restrict__ ew,
                         int* __restrict__ flags) {
    if (threadIdx.x == 0 && blockIdx.x == 0) {
        int all_lo_zero = 1, huge = 0;
        for (int i = 0; i < 256; ++i) {
            unsigned lo = xw[i] & 0xFFFFu;
            if (lo != 0u) all_lo_zero = 0;
            unsigned ex = (lo >> 7) & 0xFFu;
            if (ex >= 0xC0u) huge = 1;
        }
        flags[0] = (all_lo_zero || huge) ? 1 : 0;
        int i64 = 1;
        for (int i = 1; i < 256; i += 2) if (ew[i] != 0u) i64 = 0;
        flags[1] = i64;
    }
}

// ---------------- edge decode helpers ----------------------------------------
template <typename IT>
__device__ __forceinline__ void get_sd(const IT* __restrict__ ei, int idx, int& s, int& d) {
    if (idx < EE) { s = (int)ei[idx]; d = (int)ei[EE + idx]; }
    else          { s = d = idx - EE; }
}
template <typename IT>
__device__ __forceinline__ int dst_of(const IT* __restrict__ ei, int idx) {
    return idx < EE ? (int)ei[EE + idx] : idx - EE;
}

// ---------------- Layer 1 linear via MFMA: h1(bf16) = x @ W1, + logits --------
#define MROWS 64
#define LDK 136   // padded LDS row stride (elements) -> 272 B, 16B-aligned frags

__global__ __launch_bounds__(256) void k_lin1_mfma(
    const void* xv, const void* W1v, const void* as1v, const void* ad1v,
    const int* __restrict__ flags, bf16* __restrict__ h1,
    float* __restrict__ als, float* __restrict__ ald)
{
    __shared__ __align__(16) char smem[(MROWS + 128) * LDK * 2];  // 52,224 B
    unsigned short* xs  = (unsigned short*)smem;       // [MROWS][LDK] bf16 bits
    unsigned short* w1t = xs + MROWS * LDK;            // [128][LDK]   (n-major)
    float* hs = (float*)smem;                          // phase2 alias: [MROWS][132]
    __shared__ float sa[F1], sd[F1];

    const int t = threadIdx.x;
    const int row0 = blockIdx.x * MROWS;
    const int f32in = flags[0];

    if (t < F1) {
        sa[t] = f32in ? ((const float*)as1v)[t] : cvt(((const bf16*)as1v)[t]);
        sd[t] = f32in ? ((const float*)ad1v)[t] : cvt(((const bf16*)ad1v)[t]);
    }
    if (!f32in) {
        const uint4* xg = (const uint4*)xv;            // 16 B = 8 bf16
        for (int i = 0; i < 4; ++i) {
            int id = i * 256 + t;                      // 0..1023
            int m = id >> 4, seg = id & 15;
            int gr = row0 + m;
            uint4 val = (gr < NN) ? xg[(size_t)gr * 16 + seg] : make_uint4(0, 0, 0, 0);
            *(uint4*)&xs[m * LDK + seg * 8] = val;
        }
        const unsigned short* wg = (const unsigned short*)W1v;
        for (int i = 0; i < 64; ++i) {
            int id = i * 256 + t;                      // 0..16383
            int k = id >> 7, n = id & 127;
            w1t[n * LDK + k] = wg[id];
        }
    } else {
        const float* xf = (const float*)xv;
        for (int i = 0; i < 32; ++i) {
            int id = i * 256 + t;
            int m = id >> 7, c = id & 127;
            int gr = row0 + m;
            xs[m * LDK + c] = (gr < NN) ? f2bf_bits(xf[(size_t)gr * 128 + c]) : 0;
        }
        const float* wf = (const float*)W1v;
        for (int i = 0; i < 64; ++i) {
            int id = i * 256 + t;
            int k = id >> 7, n = id & 127;
            w1t[n * LDK + k] = f2bf_bits(wf[id]);
        }
    }
    __syncthreads();

    const int wave = t >> 6, lane = t & 63, quad = lane >> 4, l16 = lane & 15;
    f32x4 acc[8];
#pragma unroll
    for (int ni = 0; ni < 8; ++ni) acc[ni] = (f32x4){0.f, 0.f, 0.f, 0.f};

    const int arow = wave * 16 + l16;
#pragma unroll
    for (int kc = 0; kc < 4; ++kc) {
        int ko = kc * 32 + quad * 8;
        bf16x8 av = *(const bf16x8*)&xs[arow * LDK + ko];
#pragma unroll
        for (int ni = 0; ni < 8; ++ni) {
            bf16x8 bv = *(const bf16x8*)&w1t[(ni * 16 + l16) * LDK + ko];
            acc[ni] = __builtin_amdgcn_mfma_f32_16x16x32_bf16(av, bv, acc[ni], 0, 0, 0);
        }
    }
    __syncthreads();   // staging LDS dead; reuse as hs

#pragma unroll
    for (int ni = 0; ni < 8; ++ni)
#pragma unroll
        for (int r = 0; r < 4; ++r) {
            int m = wave * 16 + quad * 4 + r;          // C/D: row=quad*4+reg, col=l16
            hs[m * 132 + ni * 16 + l16] = acc[ni][r];
        }
    __syncthreads();

    for (int i = 0; i < 32; ++i) {
        int id = i * 256 + t;                          // 0..8191
        int m = id >> 7, c = id & 127;
        int gr = row0 + m;
        if (gr < NN)
            h1[(size_t)gr * 128 + c] = __float2bfloat16(hs[m * 132 + c]);
    }
    {
        int m = t >> 2, h = t & 3;                     // 64 nodes x 4 heads
        int gr = row0 + m;
        if (gr < NN) {
            float ps = 0.f, pd = 0.f;
#pragma unroll
            for (int j = 0; j < 32; ++j) {
                float v = hs[m * 132 + h * 32 + j];
                ps += v * sa[h * 32 + j];
                pd += v * sd[h * 32 + j];
            }
            als[gr * 4 + h] = ps;
            ald[gr * 4 + h] = pd;
        }
    }
}

// ---------------- CSR build: histogram + 3-phase multi-block scan + scatter ---
#define SCAN_B 196   // ceil(NN/256)

__global__ void k_hist(const void* ei, const int* __restrict__ flags,
                       int* __restrict__ counts) {
    int idx = blockIdx.x * blockDim.x + threadIdx.x;
    if (idx >= EN) return;
    int d = flags[1] ? dst_of<long long>((const long long*)ei, idx)
                     : dst_of<int>((const int*)ei, idx);
    atomicAdd(&counts[d], 1);
}

__global__ void k_scanA(const int* __restrict__ counts, int* __restrict__ bsum) {
    __shared__ int sh[256];
    int i = blockIdx.x * 256 + threadIdx.x;
    sh[threadIdx.x] = (i < NN) ? counts[i] : 0;
    __syncthreads();
    for (int off = 128; off > 0; off >>= 1) {
        if (threadIdx.x < off) sh[threadIdx.x] += sh[threadIdx.x + off];
        __syncthreads();
    }
    if (threadIdx.x == 0) bsum[blockIdx.x] = sh[0];
}

__global__ void k_scanB(const int* __restrict__ bsum, int* __restrict__ bbase) {
    __shared__ int sh[256];
    int t = threadIdx.x;
    int v = (t < SCAN_B) ? bsum[t] : 0;
    sh[t] = v;
    __syncthreads();
    for (int off = 1; off < 256; off <<= 1) {
        int u = (t >= off) ? sh[t - off] : 0;
        __syncthreads();
        sh[t] += u;
        __syncthreads();
    }
    if (t < SCAN_B) bbase[t] = sh[t] - v;   // exclusive prefix of block sums
}

__global__ void k_scanC(int* __restrict__ counts, const int* __restrict__ bbase,
                        int* __restrict__ offsets) {
    __shared__ int sh[256];
    int t = threadIdx.x;
    int i = blockIdx.x * 256 + t;
    int v = (i < NN) ? counts[i] : 0;
    sh[t] = v;
    __syncthreads();
    for (int off = 1; off < 256; off <<= 1) {
        int u = (t >= off) ? sh[t - off] : 0;
        __syncthreads();
        sh[t] += u;
        __syncthreads();
    }
    if (i < NN) {
        offsets[i] = bbase[blockIdx.x] + sh[t] - v;
        counts[i] = 0;                       // becomes the scatter cursor
    } else if (i == NN) {
        offsets[NN] = EN;                    // total is static
    }
}

// scatter SOURCE node ids into CSR order -> no 2nd indirection in aggregates
__global__ void k_scatter(const void* ei, const int* __restrict__ flags,
                          const int* __restrict__ offsets, int* __restrict__ cursor,
                          int* __restrict__ srcs) {
    int idx = blockIdx.x * blockDim.x + threadIdx.x;
    if (idx >= EN) return;
    int s, d;
    if (flags[1]) get_sd<long long>((const long long*)ei, idx, s, d);
    else          get_sd<int>((const int*)ei, idx, s, d);
    int slot = offsets[d] + atomicAdd(&cursor[d], 1);
    srcs[slot] = s;
}

// ---- Layer 1 aggregate: 1 wave/node, half-wave per edge, unroll x2,
//      fused bias+ELU, bf16 output (hm) ----------------------------------------
__global__ __launch_bounds__(256) void k_agg1(
    const int* __restrict__ offsets, const int* __restrict__ srcs,
    const float* __restrict__ als, const float* __restrict__ ald,
    const bf16* __restrict__ h1, const void* b1v, const int* __restrict__ flags,
    uint2* __restrict__ hm)
{
    const int lane = threadIdx.x & 63;
    const int d = blockIdx.x * 4 + (threadIdx.x >> 6);
    const int q = lane >> 5;           // half: even/odd edges
    const int c2 = lane & 31;          // uint2 index in row -> channels 4c2..4c2+3
    const int h = c2 >> 3;             // head of these channels
    const int start = offsets[d], end = offsets[d + 1];
    const float adv = ald[d * 4 + h];
    const uint2* rows = (const uint2*)h1;   // 32 uint2 per 256 B row

    float a0 = 0.f, a1 = 0.f, a2 = 0.f, a3 = 0.f, ds0 = 0.f;
    float b0 = 0.f, b1 = 0.f, b2 = 0.f, b3 = 0.f, ds1 = 0.f;
    int e = start + q;
    for (; e + 2 < end; e += 4) {
        int s0 = srcs[e], s1 = srcs[e + 2];
        float ev0 = als[s0 * 4 + h] + adv;
        float ev1 = als[s1 * 4 + h] + adv;
        ev0 = ev0 > 0.f ? ev0 : NEG * ev0;
        ev1 = ev1 > 0.f ? ev1 : NEG * ev1;
        float ex0 = __expf(ev0), ex1 = __expf(ev1);
        uint2 u0 = rows[s0 * 32 + c2];
        uint2 u1 = rows[s1 * 32 + c2];
        a0 += ex0 * bflo(u0.x); a1 += ex0 * bfhi(u0.x);
        a2 += ex0 * bflo(u0.y); a3 += ex0 * bfhi(u0.y); ds0 += ex0;
        b0 += ex1 * bflo(u1.x); b1 += ex1 * bfhi(u1.x);
        b2 += ex1 * bflo(u1.y); b3 += ex1 * bfhi(u1.y); ds1 += ex1;
    }
    for (; e < end; e += 2) {
        int s0 = srcs[e];
        float ev0 = als[s0 * 4 + h] + adv;
        ev0 = ev0 > 0.f ? ev0 : NEG * ev0;
        float ex0 = __expf(ev0);
        uint2 u0 = rows[s0 * 32 + c2];
        a0 += ex0 * bflo(u0.x); a1 += ex0 * bfhi(u0.x);
        a2 += ex0 * bflo(u0.y); a3 += ex0 * bfhi(u0.y); ds0 += ex0;
    }
    a0 += b0; a1 += b1; a2 += b2; a3 += b3;
    float dsum = ds0 + ds1;
    a0 += __shfl_xor(a0, 32); a1 += __shfl_xor(a1, 32);
    a2 += __shfl_xor(a2, 32); a3 += __shfl_xor(a3, 32);
    dsum += __shfl_xor(dsum, 32);
    if (q == 0) {
        float inv = 1.f / (dsum + 1e-16f);
        float bb0, bb1, bb2, bb3;
        if (flags[0]) {
            float4 bb = ((const float4*)b1v)[c2];
            bb0 = bb.x; bb1 = bb.y; bb2 = bb.z; bb3 = bb.w;
        } else {
            uint2 ub = ((const uint2*)b1v)[c2];
            bb0 = bflo(ub.x); bb1 = bfhi(ub.x); bb2 = bflo(ub.y); bb3 = bfhi(ub.y);
        }
        float v0 = a0 * inv + bb0, v1 = a1 * inv + bb1;
        float v2 = a2 * inv + bb2, v3 = a3 * inv + bb3;
        v0 = v0 > 0.f ? v0 : (__expf(v0) - 1.f);   // ELU
        v1 = v1 > 0.f ? v1 : (__expf(v1) - 1.f);
        v2 = v2 > 0.f ? v2 : (__expf(v2) - 1.f);
        v3 = v3 > 0.f ? v3 : (__expf(v3) - 1.f);
        unsigned w0 = (unsigned)f2bf_bits(v0) | ((unsigned)f2bf_bits(v1) << 16);
        unsigned w1 = (unsigned)f2bf_bits(v2) | ((unsigned)f2bf_bits(v3) << 16);
        hm[(size_t)d * 32 + c2] = make_uint2(w0, w1);
    }
}

// ---------------- Mid via MFMA: h2 = hm @ W2 (f32 out), + layer-2 logits ------
__global__ __launch_bounds__(256) void k_mid_mfma(
    const bf16* __restrict__ hm, const void* W2v, const void* as2v, const void* ad2v,
    const int* __restrict__ flags, float* __restrict__ h2,
    float* __restrict__ als2, float* __restrict__ ald2)
{
    __shared__ __align__(16) unsigned short hs[MROWS * LDK];   // 17,408 B
    __shared__ __align__(16) unsigned short w2t[32 * LDK];     // 8,704 B
    __shared__ float sa2[HID], sd2[HID];

    const int t = threadIdx.x;
    const int row0 = blockIdx.x * MROWS;
    const int f32in = flags[0];

    if (t < HID) {
        sa2[t] = f32in ? ((const float*)as2v)[t] : cvt(((const bf16*)as2v)[t]);
        sd2[t] = f32in ? ((const float*)ad2v)[t] : cvt(((const bf16*)ad2v)[t]);
    }
    {
        const uint4* hg = (const uint4*)hm;
        for (int i = 0; i < 4; ++i) {
            int id = i * 256 + t;                      // 0..1023
            int m = id >> 4, seg = id & 15;
            int gr = row0 + m;
            uint4 val = (gr < NN) ? hg[(size_t)gr * 16 + seg] : make_uint4(0, 0, 0, 0);
            *(uint4*)&hs[m * LDK + seg * 8] = val;
        }
        const unsigned short* wg = (const unsigned short*)W2v;
        const float* wf = (const float*)W2v;
        for (int i = 0; i < 16; ++i) {
            int id = i * 256 + t;                      // 0..4095 = k*32+n
            int k = id >> 5, n = id & 31;
            w2t[n * LDK + k] = f32in ? f2bf_bits(wf[id]) : wg[id];
        }
    }
    __syncthreads();

    const int wave = t >> 6, lane = t & 63, quad = lane >> 4, l16 = lane & 15;
    f32x4 acc[2];
    acc[0] = (f32x4){0.f, 0.f, 0.f, 0.f};
    acc[1] = (f32x4){0.f, 0.f, 0.f, 0.f};
    const int arow = wave * 16 + l16;
#pragma unroll
    for (int kc = 0; kc < 4; ++kc) {
        int ko = kc * 32 + quad * 8;
        bf16x8 av = *(const bf16x8*)&hs[arow * LDK + ko];
#pragma unroll
        for (int ni = 0; ni < 2; ++ni) {
            bf16x8 bv = *(const bf16x8*)&w2t[(ni * 16 + l16) * LDK + ko];
            acc[ni] = __builtin_amdgcn_mfma_f32_16x16x32_bf16(av, bv, acc[ni], 0, 0, 0);
        }
    }

    // h2 stores straight from registers (C/D: row=quad*4+r, col=ni*16+l16)
#pragma unroll
    for (int ni = 0; ni < 2; ++ni)
#pragma unroll
        for (int r = 0; r < 4; ++r) {
            int gr = row0 + wave * 16 + quad * 4 + r;
            if (gr < NN) h2[(size_t)gr * 32 + ni * 16 + l16] = acc[ni][r];
        }

    // logits: per-row dot with a_src2/a_dst2, 16-lane butterfly reduction
    float ps[4], pd[4];
#pragma unroll
    for (int r = 0; r < 4; ++r) {
        ps[r] = acc[0][r] * sa2[l16] + acc[1][r] * sa2[16 + l16];
        pd[r] = acc[0][r] * sd2[l16] + acc[1][r] * sd2[16 + l16];
    }
#pragma unroll
    for (int mask = 1; mask < 16; mask <<= 1)
#pragma unroll
        for (int r = 0; r < 4; ++r) {
            ps[r] += __shfl_xor(ps[r], mask);
            pd[r] += __shfl_xor(pd[r], mask);
        }
    if (l16 == 0) {
#pragma unroll
        for (int r = 0; r < 4; ++r) {
            int gr = row0 + wave * 16 + quad * 4 + r;
            if (gr < NN) { als2[gr] = ps[r]; ald2[gr] = pd[r]; }
        }
    }
}

// ---- Layer 2 aggregate: 1 wave/node, half-wave per edge, unroll x2, fused b2 --
__global__ __launch_bounds__(256) void k_agg2(
    const int* __restrict__ offsets, const int* __restrict__ srcs,
    const float* __restrict__ als2, const float* __restrict__ ald2,
    const float* __restrict__ h2, const void* b2v, const int* __restrict__ flags,
    void* out)
{
    const int lane = threadIdx.x & 63;
    const int node = blockIdx.x * 4 + (threadIdx.x >> 6);
    const int q = lane >> 5, c = lane & 31;
    const int start = offsets[node], end = offsets[node + 1];
    const float adv = ald2[node];

    float acc0 = 0.f, acc1 = 0.f, ds0 = 0.f, ds1 = 0.f;
    int e = start + q;
    for (; e + 2 < end; e += 4) {
        int s0 = srcs[e], s1 = srcs[e + 2];
        float ev0 = als2[s0] + adv;
        float ev1 = als2[s1] + adv;
        ev0 = ev0 > 0.f ? ev0 : NEG * ev0;
        ev1 = ev1 > 0.f ? ev1 : NEG * ev1;
        float ex0 = __expf(ev0), ex1 = __expf(ev1);
        float v0 = h2[(size_t)s0 * 32 + c];
        float v1 = h2[(size_t)s1 * 32 + c];
        acc0 += ex0 * v0; ds0 += ex0;
        acc1 += ex1 * v1; ds1 += ex1;
    }
    for (; e < end; e += 2) {
        int s0 = srcs[e];
        float ev0 = als2[s0] + adv;
        ev0 = ev0 > 0.f ? ev0 : NEG * ev0;
        float ex0 = __expf(ev0);
        acc0 += ex0 * h2[(size_t)s0 * 32 + c]; ds0 += ex0;
    }
    float acc = acc0 + acc1, dsum = ds0 + ds1;
    acc  += __shfl_xor(acc, 32);
    dsum += __shfl_xor(dsum, 32);
    if (q == 0) {
        float r = acc / (dsum + 1e-16f);
        if (flags[0]) {
            ((float*)out)[(size_t)node * 32 + c] = r + ((const float*)b2v)[c];
        } else {
            ((bf16*)out)[(size_t)node * 32 + c] =
                __float2bfloat16(r + cvt(((const bf16*)b2v)[c]));
        }
    }
}

extern "C" void kernel_launch(void* const* d_in, const int* in_sizes, int n_in,
                              void* d_out, int out_size, void* d_ws, size_t ws_size,
                              hipStream_t stream) {
    const void* x    = d_in[0];
    const void* ei   = d_in[1];
    const void* W1   = d_in[2];
    const void* a_s1 = d_in[3];
    const void* a_d1 = d_in[4];
    const void* b1   = d_in[5];
    const void* W2   = d_in[6];
    const void* a_s2 = d_in[7];
    const void* a_d2 = d_in[8];
    const void* b2v  = d_in[9];

    // ---- workspace layout (~44.2 MB) ----
    int*   flags  = (int*)d_ws;
    float* p      = (float*)d_ws + 64;
    uint2* hm     = (uint2*)p; p += (size_t)NN * F1;     // bf16 [NN][128] in 25.6MB slot
    bf16*  h1     = (bf16*)p; p += (size_t)NN * F1 / 2;  // 12.8 MB; reused as f32 h2
    float* h2     = (float*)h1;                          // alias (h1 dead after k_agg1)
    float* al_s1  = p; p += (size_t)NN * HEADS;
    float* al_d1  = p; p += (size_t)NN * HEADS;
    float* al_s2  = p; p += NN;
    float* al_d2  = p; p += NN;
    int*   offs   = (int*)p; p += NN + 1;
    int*   counts = (int*)p; p += NN;                    // doubles as scatter cursor
    int*   srcs   = (int*)p; p += EN;                    // 3.4 MB (CSR source ids)
    int*   bsum   = (int*)p; p += SCAN_B;
    int*   bbase  = (int*)p; p += SCAN_B;

    hipMemsetAsync(counts, 0, (size_t)NN * sizeof(int), stream);

    k_detect<<<1, 64, 0, stream>>>((const unsigned*)x, (const unsigned*)ei, flags);
    k_hist<<<(EN + 255) / 256, 256, 0, stream>>>(ei, flags, counts);
    k_scanA<<<SCAN_B, 256, 0, stream>>>(counts, bsum);
    k_scanB<<<1, 256, 0, stream>>>(bsum, bbase);
    k_scanC<<<SCAN_B, 256, 0, stream>>>(counts, bbase, offs);
    k_scatter<<<(EN + 255) / 256, 256, 0, stream>>>(ei, flags, offs, counts, srcs);
    k_lin1_mfma<<<(NN + MROWS - 1) / MROWS, 256, 0, stream>>>(x, W1, a_s1, a_d1,
                                                              flags, h1, al_s1, al_d1);
    k_agg1<<<NN / 4, 256, 0, stream>>>(offs, srcs, al_s1, al_d1, h1, b1, flags, hm);
    k_mid_mfma<<<(NN + MROWS - 1) / MROWS, 256, 0, stream>>>((const bf16*)hm, W2, a_s2,
                                                             a_d2, flags, h2, al_s2, al_d2);
    k_agg2<<<NN / 4, 256, 0, stream>>>(offs, srcs, al_s2, al_d2, h2, b2v, flags, d_out);
}

// Round 8
// 290.107 us; speedup vs baseline: 3.2268x; 1.0569x over previous
//
#include <hip/hip_runtime.h>
#include <hip/hip_bf16.h>

#define NN 50000
#define EE 800000
#define EN (EE + NN)      // edges including self-loops
#define IN_DIM 128
#define HID 32
#define HEADS 4
#define F1 (HEADS * HID)  // 128
#define NEG 0.2f

typedef __hip_bfloat16 bf16;
typedef __bf16 bf16x8 __attribute__((ext_vector_type(8)));
typedef float f32x4 __attribute__((ext_vector_type(4)));

__device__ __forceinline__ float cvt(float v) { return v; }
__device__ __forceinline__ float cvt(bf16 v)  { return __bfloat162float(v); }

__device__ __forceinline__ float bflo(unsigned u) {
    union { unsigned u; float f; } v; v.u = u << 16; return v.f;
}
__device__ __forceinline__ float bfhi(unsigned u) {
    union { unsigned u; float f; } v; v.u = u & 0xFFFF0000u; return v.f;
}

__device__ __forceinline__ unsigned short f2bf_bits(float f) {
    union { float f; unsigned u; } v; v.f = f;
    unsigned r = v.u + 0x7FFFu + ((v.u >> 16) & 1u);
    return (unsigned short)(r >> 16);
}

__device__ __forceinline__ unsigned short f2h_bits(float f) {
    _Float16 h = (_Float16)f;
    union { _Float16 h; unsigned short s; } v; v.h = h; return v.s;
}
__device__ __forceinline__ float h2f(unsigned short s) {
    union { _Float16 h; unsigned short s; } v; v.s = s; return (float)v.h;
}

// ---------------- dtype detector (parallel): flags[0]=f32, flags[1]=i64 -------
__global__ void k_detect(const unsigned* __restrict__ xw, const unsigned* __restrict__ ew,
                         int* __restrict__ flags) {
    const int t = threadIdx.x;   // 64 lanes
    int lo_nz = 0, huge = 0, hi_nz = 0;
    for (int j = 0; j < 4; ++j) {
        unsigned w = xw[t * 4 + j];
        unsigned lo = w & 0xFFFFu;
        if (lo != 0u) lo_nz = 1;
        if (((lo >> 7) & 0xFFu) >= 0xC0u) huge = 1;
        unsigned eo = ew[(t * 4 + j) * 2 + 1];   // odd 32-bit words of edge array
        if (eo != 0u) hi_nz = 1;
    }
    unsigned long long m_lo = __ballot(lo_nz);
    unsigned long long m_hg = __ballot(huge);
    unsigned long long m_hi = __ballot(hi_nz);
    if (t == 0) {
        flags[0] = (m_lo == 0ull || m_hg != 0ull) ? 1 : 0;   // all-lo-zero or huge => f32
        flags[1] = (m_hi == 0ull) ? 1 : 0;                   // all odd words zero => i64
    }
}

// ---------------- prep: W1T[n][k], W2T[n][k] as bf16 --------------------------
__global__ void k_prep(const void* W1v, const void* W2v, const int* __restrict__ flags,
                       unsigned short* __restrict__ W1T, unsigned short* __restrict__ W2T) {
    const int t = threadIdx.x;
    const int f32in = flags[0];
    const unsigned short* w1g = (const unsigned short*)W1v;
    const float* w1f = (const float*)W1v;
    for (int i = 0; i < 64; ++i) {
        int id = i * 256 + t;                 // n*128+k
        int n = id >> 7, k = id & 127;
        W1T[id] = f32in ? f2bf_bits(w1f[k * 128 + n]) : w1g[k * 128 + n];
    }
    const unsigned short* w2g = (const unsigned short*)W2v;
    const float* w2f = (const float*)W2v;
    for (int i = 0; i < 16; ++i) {
        int id = i * 256 + t;                 // n*128+k  (n<32)
        int n = id >> 7, k = id & 127;
        W2T[id] = f32in ? f2bf_bits(w2f[k * 32 + n]) : w2g[k * 32 + n];
    }
}

// ---------------- edge decode helpers ----------------------------------------
template <typename IT>
__device__ __forceinline__ void get_sd(const IT* __restrict__ ei, int idx, int& s, int& d) {
    if (idx < EE) { s = (int)ei[idx]; d = (int)ei[EE + idx]; }
    else          { s = d = idx - EE; }
}
template <typename IT>
__device__ __forceinline__ int dst_of(const IT* __restrict__ ei, int idx) {
    return idx < EE ? (int)ei[EE + idx] : idx - EE;
}

// ---------------- Layer 1 linear via MFMA: h1(bf16) = x @ W1, + logits --------
#define MROWS 64
#define LDK 136   // padded LDS row stride (elements) -> 272 B, 16B-aligned frags

__global__ __launch_bounds__(256) void k_lin1_mfma(
    const void* xv, const unsigned short* __restrict__ W1T,
    const void* as1v, const void* ad1v,
    const int* __restrict__ flags, bf16* __restrict__ h1,
    float* __restrict__ als, float* __restrict__ ald)
{
    __shared__ __align__(16) char smem[(MROWS + 128) * LDK * 2];  // 52,224 B
    unsigned short* xs  = (unsigned short*)smem;       // [MROWS][LDK] bf16 bits
    unsigned short* w1t = xs + MROWS * LDK;            // [128][LDK]   (n-major)
    float* hs = (float*)smem;                          // phase2 alias: [MROWS][132]
    __shared__ float sa[F1], sd[F1];

    const int t = threadIdx.x;
    const int row0 = blockIdx.x * MROWS;
    const int f32in = flags[0];

    if (t < F1) {
        sa[t] = f32in ? ((const float*)as1v)[t] : cvt(((const bf16*)as1v)[t]);
        sd[t] = f32in ? ((const float*)ad1v)[t] : cvt(((const bf16*)ad1v)[t]);
    }
    if (!f32in) {
        const uint4* xg = (const uint4*)xv;            // 16 B = 8 bf16
        for (int i = 0; i < 4; ++i) {
            int id = i * 256 + t;                      // 0..1023
            int m = id >> 4, seg = id & 15;
            int gr = row0 + m;
            uint4 val = (gr < NN) ? xg[(size_t)gr * 16 + seg] : make_uint4(0, 0, 0, 0);
            *(uint4*)&xs[m * LDK + seg * 8] = val;
        }
    } else {
        const float* xf = (const float*)xv;
        for (int i = 0; i < 32; ++i) {
            int id = i * 256 + t;
            int m = id >> 7, c = id & 127;
            int gr = row0 + m;
            xs[m * LDK + c] = (gr < NN) ? f2bf_bits(xf[(size_t)gr * 128 + c]) : 0;
        }
    }
    {
        const uint4* wg = (const uint4*)W1T;           // [128][16] uint4, n-major
        for (int i = 0; i < 8; ++i) {
            int id = i * 256 + t;                      // 0..2047 = n*16+seg
            int n = id >> 4, seg = id & 15;
            *(uint4*)&w1t[n * LDK + seg * 8] = wg[id];
        }
    }
    __syncthreads();

    const int wave = t >> 6, lane = t & 63, quad = lane >> 4, l16 = lane & 15;
    f32x4 acc[8];
#pragma unroll
    for (int ni = 0; ni < 8; ++ni) acc[ni] = (f32x4){0.f, 0.f, 0.f, 0.f};

    const int arow = wave * 16 + l16;
#pragma unroll
    for (int kc = 0; kc < 4; ++kc) {
        int ko = kc * 32 + quad * 8;
        bf16x8 av = *(const bf16x8*)&xs[arow * LDK + ko];
#pragma unroll
        for (int ni = 0; ni < 8; ++ni) {
            bf16x8 bv = *(const bf16x8*)&w1t[(ni * 16 + l16) * LDK + ko];
            acc[ni] = __builtin_amdgcn_mfma_f32_16x16x32_bf16(av, bv, acc[ni], 0, 0, 0);
        }
    }
    __syncthreads();   // staging LDS dead; reuse as hs

#pragma unroll
    for (int ni = 0; ni < 8; ++ni)
#pragma unroll
        for (int r = 0; r < 4; ++r) {
            int m = wave * 16 + quad * 4 + r;          // C/D: row=quad*4+reg, col=l16
            hs[m * 132 + ni * 16 + l16] = acc[ni][r];
        }
    __syncthreads();

    for (int i = 0; i < 32; ++i) {
        int id = i * 256 + t;                          // 0..8191
        int m = id >> 7, c = id & 127;
        int gr = row0 + m;
        if (gr < NN)
            h1[(size_t)gr * 128 + c] = __float2bfloat16(hs[m * 132 + c]);
    }
    {
        int m = t >> 2, h = t & 3;                     // 64 nodes x 4 heads
        int gr = row0 + m;
        if (gr < NN) {
            float ps = 0.f, pd = 0.f;
#pragma unroll
            for (int j = 0; j < 32; ++j) {
                float v = hs[m * 132 + h * 32 + j];
                ps += v * sa[h * 32 + j];
                pd += v * sd[h * 32 + j];
            }
            als[gr * 4 + h] = ps;
            ald[gr * 4 + h] = pd;
        }
    }
}

// ---------------- CSR build: histogram + 3-phase multi-block scan -------------
#define SCAN_B 196   // ceil(NN/256)

__global__ void k_hist(const void* ei, const int* __restrict__ flags,
                       int* __restrict__ counts) {
    int idx = blockIdx.x * blockDim.x + threadIdx.x;
    if (idx >= EN) return;
    int d = flags[1] ? dst_of<long long>((const long long*)ei, idx)
                     : dst_of<int>((const int*)ei, idx);
    atomicAdd(&counts[d], 1);
}

__global__ void k_scanA(const int* __restrict__ counts, int* __restrict__ bsum) {
    __shared__ int sh[256];
    int i = blockIdx.x * 256 + threadIdx.x;
    sh[threadIdx.x] = (i < NN) ? counts[i] : 0;
    __syncthreads();
    for (int off = 128; off > 0; off >>= 1) {
        if (threadIdx.x < off) sh[threadIdx.x] += sh[threadIdx.x + off];
        __syncthreads();
    }
    if (threadIdx.x == 0) bsum[blockIdx.x] = sh[0];
}

__global__ void k_scanB(const int* __restrict__ bsum, int* __restrict__ bbase) {
    __shared__ int sh[256];
    int t = threadIdx.x;
    int v = (t < SCAN_B) ? bsum[t] : 0;
    sh[t] = v;
    __syncthreads();
    for (int off = 1; off < 256; off <<= 1) {
        int u = (t >= off) ? sh[t - off] : 0;
        __syncthreads();
        sh[t] += u;
        __syncthreads();
    }
    if (t < SCAN_B) bbase[t] = sh[t] - v;   // exclusive prefix of block sums
}

__global__ void k_scanC(int* __restrict__ counts, const int* __restrict__ bbase,
                        int* __restrict__ offsets) {
    __shared__ int sh[256];
    int t = threadIdx.x;
    int i = blockIdx.x * 256 + t;
    int v = (i < NN) ? counts[i] : 0;
    sh[t] = v;
    __syncthreads();
    for (int off = 1; off < 256; off <<= 1) {
        int u = (t >= off) ? sh[t - off] : 0;
        __syncthreads();
        sh[t] += u;
        __syncthreads();
    }
    if (i < NN) {
        offsets[i] = bbase[blockIdx.x] + sh[t] - v;
        counts[i] = 0;                       // becomes the scatter cursor
    } else if (i == NN) {
        offsets[NN] = EN;                    // total is static
    }
}

// ---- scatter: CSR src ids + per-edge per-head exp weights (f16x4, 8 B) -------
__global__ void k_scatter(const void* ei, const int* __restrict__ flags,
                          const int* __restrict__ offsets, int* __restrict__ cursor,
                          const float4* __restrict__ als, const float4* __restrict__ ald,
                          int* __restrict__ srcs, uint2* __restrict__ expe1) {
    int idx = blockIdx.x * blockDim.x + threadIdx.x;
    if (idx >= EN) return;
    int s, d;
    if (flags[1]) get_sd<long long>((const long long*)ei, idx, s, d);
    else          get_sd<int>((const int*)ei, idx, s, d);
    int slot = offsets[d] + atomicAdd(&cursor[d], 1);
    srcs[slot] = s;
    float4 a = als[s], b = ald[d];
    float e0 = a.x + b.x, e1 = a.y + b.y, e2 = a.z + b.z, e3 = a.w + b.w;
    e0 = e0 > 0.f ? e0 : NEG * e0;
    e1 = e1 > 0.f ? e1 : NEG * e1;
    e2 = e2 > 0.f ? e2 : NEG * e2;
    e3 = e3 > 0.f ? e3 : NEG * e3;
    unsigned w0 = (unsigned)f2h_bits(__expf(e0)) | ((unsigned)f2h_bits(__expf(e1)) << 16);
    unsigned w1 = (unsigned)f2h_bits(__expf(e2)) | ((unsigned)f2h_bits(__expf(e3)) << 16);
    expe1[slot] = make_uint2(w0, w1);
}

// ---- Layer 1 aggregate: 1 wave/node, half-wave/edge, unroll x4, precomp exp,
//      fused bias+ELU, bf16 output (hm) ----------------------------------------
__global__ __launch_bounds__(256) void k_agg1(
    const int* __restrict__ offsets, const int* __restrict__ srcs,
    const unsigned short* __restrict__ expe1,   // f16 bits, [EN][4]
    const bf16* __restrict__ h1, const void* b1v, const int* __restrict__ flags,
    uint2* __restrict__ hm)
{
    const int lane = threadIdx.x & 63;
    const int d = blockIdx.x * 4 + (threadIdx.x >> 6);
    const int q = lane >> 5;           // half: even/odd edges
    const int u = lane & 31;           // uint2 index in row -> channels 4u..4u+3
    const int h = u >> 3;              // head of these channels
    const int start = offsets[d], end = offsets[d + 1];
    const uint2* rows = (const uint2*)h1;   // 32 uint2 per 256 B row

    float A0[4] = {0,0,0,0}, A1[4] = {0,0,0,0}, A2[4] = {0,0,0,0}, A3[4] = {0,0,0,0};
    float D[4] = {0,0,0,0};
    int e = start + q;
    for (; e + 6 < end; e += 8) {
        int s0 = srcs[e],     s1 = srcs[e + 2];
        int s2 = srcs[e + 4], s3 = srcs[e + 6];
        float x0 = h2f(expe1[(size_t)e * 4 + h]);
        float x1 = h2f(expe1[(size_t)(e + 2) * 4 + h]);
        float x2 = h2f(expe1[(size_t)(e + 4) * 4 + h]);
        float x3 = h2f(expe1[(size_t)(e + 6) * 4 + h]);
        uint2 u0 = rows[s0 * 32 + u], u1 = rows[s1 * 32 + u];
        uint2 u2 = rows[s2 * 32 + u], u3 = rows[s3 * 32 + u];
        A0[0] += x0 * bflo(u0.x); A0[1] += x0 * bfhi(u0.x);
        A0[2] += x0 * bflo(u0.y); A0[3] += x0 * bfhi(u0.y); D[0] += x0;
        A1[0] += x1 * bflo(u1.x); A1[1] += x1 * bfhi(u1.x);
        A1[2] += x1 * bflo(u1.y); A1[3] += x1 * bfhi(u1.y); D[1] += x1;
        A2[0] += x2 * bflo(u2.x); A2[1] += x2 * bfhi(u2.x);
        A2[2] += x2 * bflo(u2.y); A2[3] += x2 * bfhi(u2.y); D[2] += x2;
        A3[0] += x3 * bflo(u3.x); A3[1] += x3 * bfhi(u3.x);
        A3[2] += x3 * bflo(u3.y); A3[3] += x3 * bfhi(u3.y); D[3] += x3;
    }
    for (; e < end; e += 2) {
        int s0 = srcs[e];
        float x0 = h2f(expe1[(size_t)e * 4 + h]);
        uint2 u0 = rows[s0 * 32 + u];
        A0[0] += x0 * bflo(u0.x); A0[1] += x0 * bfhi(u0.x);
        A0[2] += x0 * bflo(u0.y); A0[3] += x0 * bfhi(u0.y); D[0] += x0;
    }
    float a0 = A0[0] + A1[0] + A2[0] + A3[0];
    float a1 = A0[1] + A1[1] + A2[1] + A3[1];
    float a2 = A0[2] + A1[2] + A2[2] + A3[2];
    float a3 = A0[3] + A1[3] + A2[3] + A3[3];
    float dsum = D[0] + D[1] + D[2] + D[3];
    a0 += __shfl_xor(a0, 32); a1 += __shfl_xor(a1, 32);
    a2 += __shfl_xor(a2, 32); a3 += __shfl_xor(a3, 32);
    dsum += __shfl_xor(dsum, 32);
    if (q == 0) {
        float inv = 1.f / (dsum + 1e-16f);
        float bb0, bb1, bb2, bb3;
        if (flags[0]) {
            float4 bb = ((const float4*)b1v)[u];
            bb0 = bb.x; bb1 = bb.y; bb2 = bb.z; bb3 = bb.w;
        } else {
            uint2 ub = ((const uint2*)b1v)[u];
            bb0 = bflo(ub.x); bb1 = bfhi(ub.x); bb2 = bflo(ub.y); bb3 = bfhi(ub.y);
        }
        float v0 = a0 * inv + bb0, v1 = a1 * inv + bb1;
        float v2 = a2 * inv + bb2, v3 = a3 * inv + bb3;
        v0 = v0 > 0.f ? v0 : (__expf(v0) - 1.f);   // ELU
        v1 = v1 > 0.f ? v1 : (__expf(v1) - 1.f);
        v2 = v2 > 0.f ? v2 : (__expf(v2) - 1.f);
        v3 = v3 > 0.f ? v3 : (__expf(v3) - 1.f);
        unsigned w0 = (unsigned)f2bf_bits(v0) | ((unsigned)f2bf_bits(v1) << 16);
        unsigned w1 = (unsigned)f2bf_bits(v2) | ((unsigned)f2bf_bits(v3) << 16);
        hm[(size_t)d * 32 + u] = make_uint2(w0, w1);
    }
}

// ---------------- Mid via MFMA: h2 = hm @ W2 (f32 out), + layer-2 logits ------
__global__ __launch_bounds__(256) void k_mid_mfma(
    const bf16* __restrict__ hm, const unsigned short* __restrict__ W2T,
    const void* as2v, const void* ad2v,
    const int* __restrict__ flags, float* __restrict__ h2,
    float* __restrict__ als2, float* __restrict__ ald2)
{
    __shared__ __align__(16) unsigned short hs[MROWS * LDK];   // 17,408 B
    __shared__ __align__(16) unsigned short w2t[32 * LDK];     // 8,704 B
    __shared__ float sa2[HID], sd2[HID];

    const int t = threadIdx.x;
    const int row0 = blockIdx.x * MROWS;
    const int f32in = flags[0];

    if (t < HID) {
        sa2[t] = f32in ? ((const float*)as2v)[t] : cvt(((const bf16*)as2v)[t]);
        sd2[t] = f32in ? ((const float*)ad2v)[t] : cvt(((const bf16*)ad2v)[t]);
    }
    {
        const uint4* hg = (const uint4*)hm;
        for (int i = 0; i < 4; ++i) {
            int id = i * 256 + t;                      // 0..1023
            int m = id >> 4, seg = id & 15;
            int gr = row0 + m;
            uint4 val = (gr < NN) ? hg[(size_t)gr * 16 + seg] : make_uint4(0, 0, 0, 0);
            *(uint4*)&hs[m * LDK + seg * 8] = val;
        }
        const uint4* wg = (const uint4*)W2T;           // [32][16] uint4, n-major
        for (int i = 0; i < 2; ++i) {
            int id = i * 256 + t;                      // 0..511 = n*16+seg
            int n = id >> 4, seg = id & 15;
            *(uint4*)&w2t[n * LDK + seg * 8] = wg[id];
        }
    }
    __syncthreads();

    const int wave = t >> 6, lane = t & 63, quad = lane >> 4, l16 = lane & 15;
    f32x4 acc[2];
    acc[0] = (f32x4){0.f, 0.f, 0.f, 0.f};
    acc[1] = (f32x4){0.f, 0.f, 0.f, 0.f};
    const int arow = wave * 16 + l16;
#pragma unroll
    for (int kc = 0; kc < 4; ++kc) {
        int ko = kc * 32 + quad * 8;
        bf16x8 av = *(const bf16x8*)&hs[arow * LDK + ko];
#pragma unroll
        for (int ni = 0; ni < 2; ++ni) {
            bf16x8 bv = *(const bf16x8*)&w2t[(ni * 16 + l16) * LDK + ko];
            acc[ni] = __builtin_amdgcn_mfma_f32_16x16x32_bf16(av, bv, acc[ni], 0, 0, 0);
        }
    }

    // h2 stores straight from registers (C/D: row=quad*4+r, col=ni*16+l16)
#pragma unroll
    for (int ni = 0; ni < 2; ++ni)
#pragma unroll
        for (int r = 0; r < 4; ++r) {
            int gr = row0 + wave * 16 + quad * 4 + r;
            if (gr < NN) h2[(size_t)gr * 32 + ni * 16 + l16] = acc[ni][r];
        }

    // logits: per-row dot with a_src2/a_dst2, 16-lane butterfly reduction
    float ps[4], pd[4];
#pragma unroll
    for (int r = 0; r < 4; ++r) {
        ps[r] = acc[0][r] * sa2[l16] + acc[1][r] * sa2[16 + l16];
        pd[r] = acc[0][r] * sd2[l16] + acc[1][r] * sd2[16 + l16];
    }
#pragma unroll
    for (int mask = 1; mask < 16; mask <<= 1)
#pragma unroll
        for (int r = 0; r < 4; ++r) {
            ps[r] += __shfl_xor(ps[r], mask);
            pd[r] += __shfl_xor(pd[r], mask);
        }
    if (l16 == 0) {
#pragma unroll
        for (int r = 0; r < 4; ++r) {
            int gr = row0 + wave * 16 + quad * 4 + r;
            if (gr < NN) { als2[gr] = ps[r]; ald2[gr] = pd[r]; }
        }
    }
}

// ---- Layer 2 aggregate: 1 wave/node, half-wave/edge, unroll x4, fused b2 -----
__global__ __launch_bounds__(256) void k_agg2(
    const int* __restrict__ offsets, const int* __restrict__ srcs,
    const float* __restrict__ als2, const float* __restrict__ ald2,
    const float* __restrict__ h2, const void* b2v, const int* __restrict__ flags,
    void* out)
{
    const int lane = threadIdx.x & 63;
    const int node = blockIdx.x * 4 + (threadIdx.x >> 6);
    const int q = lane >> 5, c = lane & 31;
    const int start = offsets[node], end = offsets[node + 1];
    const float adv = ald2[node];

    float A[4] = {0,0,0,0}, D[4] = {0,0,0,0};
    int e = start + q;
    for (; e + 6 < end; e += 8) {
        int s0 = srcs[e],     s1 = srcs[e + 2];
        int s2 = srcs[e + 4], s3 = srcs[e + 6];
        float e0 = als2[s0] + adv, e1 = als2[s1] + adv;
        float e2 = als2[s2] + adv, e3 = als2[s3] + adv;
        e0 = e0 > 0.f ? e0 : NEG * e0;  e1 = e1 > 0.f ? e1 : NEG * e1;
        e2 = e2 > 0.f ? e2 : NEG * e2;  e3 = e3 > 0.f ? e3 : NEG * e3;
        float x0 = __expf(e0), x1 = __expf(e1), x2 = __expf(e2), x3 = __expf(e3);
        float v0 = h2[(size_t)s0 * 32 + c], v1 = h2[(size_t)s1 * 32 + c];
        float v2 = h2[(size_t)s2 * 32 + c], v3 = h2[(size_t)s3 * 32 + c];
        A[0] += x0 * v0; D[0] += x0;  A[1] += x1 * v1; D[1] += x1;
        A[2] += x2 * v2; D[2] += x2;  A[3] += x3 * v3; D[3] += x3;
    }
    for (; e < end; e += 2) {
        int s0 = srcs[e];
        float e0 = als2[s0] + adv;
        e0 = e0 > 0.f ? e0 : NEG * e0;
        float x0 = __expf(e0);
        A[0] += x0 * h2[(size_t)s0 * 32 + c]; D[0] += x0;
    }
    float acc = A[0] + A[1] + A[2] + A[3];
    float dsum = D[0] + D[1] + D[2] + D[3];
    acc  += __shfl_xor(acc, 32);
    dsum += __shfl_xor(dsum, 32);
    if (q == 0) {
        float r = acc / (dsum + 1e-16f);
        if (flags[0]) {
            ((float*)out)[(size_t)node * 32 + c] = r + ((const float*)b2v)[c];
        } else {
            ((bf16*)out)[(size_t)node * 32 + c] =
                __float2bfloat16(r + cvt(((const bf16*)b2v)[c]));
        }
    }
}

extern "C" void kernel_launch(void* const* d_in, const int* in_sizes, int n_in,
                              void* d_out, int out_size, void* d_ws, size_t ws_size,
                              hipStream_t stream) {
    const void* x    = d_in[0];
    const void* ei   = d_in[1];
    const void* W1   = d_in[2];
    const void* a_s1 = d_in[3];
    const void* a_d1 = d_in[4];
    const void* b1   = d_in[5];
    const void* W2   = d_in[6];
    const void* a_s2 = d_in[7];
    const void* a_d2 = d_in[8];
    const void* b2v  = d_in[9];

    // ---- workspace layout (~38.3 MB) ----
    int*   flags  = (int*)d_ws;
    char*  pc     = (char*)d_ws + 256;
    uint2* hm     = (uint2*)pc;            pc += (size_t)NN * 32 * 8;   // bf16 [NN][128], 12.8 MB
    bf16*  h1     = (bf16*)pc;             pc += (size_t)NN * F1 * 2;   // 12.8 MB; reused as f32 h2
    float* h2     = (float*)h1;                                          // alias (6.4 MB, fits)
    uint2* expe1  = (uint2*)pc;            pc += (size_t)EN * 8;        // f16x4/edge, 6.8 MB
    float* al_s1  = (float*)pc;            pc += (size_t)NN * HEADS * 4;
    float* al_d1  = (float*)pc;            pc += (size_t)NN * HEADS * 4;
    float* al_s2  = (float*)pc;            pc += (size_t)NN * 4;
    float* al_d2  = (float*)pc;            pc += (size_t)NN * 4;
    int*   offs   = (int*)pc;              pc += (size_t)(NN + 4) * 4;
    int*   counts = (int*)pc;              pc += (size_t)NN * 4;        // scatter cursor after scanC
    int*   srcs   = (int*)pc;              pc += (size_t)EN * 4;        // 3.4 MB
    unsigned short* W1T = (unsigned short*)pc; pc += (size_t)128 * 128 * 2;
    unsigned short* W2T = (unsigned short*)pc; pc += (size_t)32 * 128 * 2;
    int*   bsum   = (int*)pc;              pc += SCAN_B * 4;
    int*   bbase  = (int*)pc;              pc += SCAN_B * 4;

    hipMemsetAsync(counts, 0, (size_t)NN * sizeof(int), stream);

    k_detect<<<1, 64, 0, stream>>>((const unsigned*)x, (const unsigned*)ei, flags);
    k_prep<<<1, 256, 0, stream>>>(W1, W2, flags, W1T, W2T);
    k_hist<<<(EN + 255) / 256, 256, 0, stream>>>(ei, flags, counts);
    k_scanA<<<SCAN_B, 256, 0, stream>>>(counts, bsum);
    k_scanB<<<1, 256, 0, stream>>>(bsum, bbase);
    k_scanC<<<SCAN_B, 256, 0, stream>>>(counts, bbase, offs);
    k_lin1_mfma<<<(NN + MROWS - 1) / MROWS, 256, 0, stream>>>(x, W1T, a_s1, a_d1,
                                                              flags, h1, al_s1, al_d1);
    k_scatter<<<(EN + 255) / 256, 256, 0, stream>>>(ei, flags, offs, counts,
                                                    (const float4*)al_s1,
                                                    (const float4*)al_d1, srcs, expe1);
    k_agg1<<<NN / 4, 256, 0, stream>>>(offs, srcs, (const unsigned short*)expe1,
                                       h1, b1, flags, hm);
    k_mid_mfma<<<(NN + MROWS - 1) / MROWS, 256, 0, stream>>>((const bf16*)hm, W2T, a_s2,
                                                             a_d2, flags, h2, al_s2, al_d2);
    k_agg2<<<NN / 4, 256, 0, stream>>>(offs, srcs, al_s2, al_d2, h2, b2v, flags, d_out);
}

// Round 9
// 266.470 us; speedup vs baseline: 3.5130x; 1.0887x over previous
//
#include <hip/hip_runtime.h>
#include <hip/hip_bf16.h>

#define NN 50000
#define EE 800000
#define EN (EE + NN)      // edges including self-loops
#define IN_DIM 128
#define HID 32
#define HEADS 4
#define F1 (HEADS * HID)  // 128
#define NEG 0.2f

typedef __hip_bfloat16 bf16;
typedef __bf16 bf16x8 __attribute__((ext_vector_type(8)));
typedef float f32x4 __attribute__((ext_vector_type(4)));

__device__ __forceinline__ float cvt(float v) { return v; }
__device__ __forceinline__ float cvt(bf16 v)  { return __bfloat162float(v); }

__device__ __forceinline__ float bflo(unsigned u) {
    union { unsigned u; float f; } v; v.u = u << 16; return v.f;
}
__device__ __forceinline__ float bfhi(unsigned u) {
    union { unsigned u; float f; } v; v.u = u & 0xFFFF0000u; return v.f;
}

__device__ __forceinline__ unsigned short f2bf_bits(float f) {
    union { float f; unsigned u; } v; v.f = f;
    unsigned r = v.u + 0x7FFFu + ((v.u >> 16) & 1u);
    return (unsigned short)(r >> 16);
}

__device__ __forceinline__ unsigned short f2h_bits(float f) {
    _Float16 h = (_Float16)f;
    union { _Float16 h; unsigned short s; } v; v.h = h; return v.s;
}
__device__ __forceinline__ float h2f(unsigned short s) {
    union { _Float16 h; unsigned short s; } v; v.s = s; return (float)v.h;
}

// exp for head h out of a packed record (y = heads 0,1 ; z = heads 2,3)
__device__ __forceinline__ float rec_exp(uint4 r, int h) {
    unsigned w = (h & 2) ? r.z : r.y;
    unsigned short b = (h & 1) ? (unsigned short)(w >> 16) : (unsigned short)(w & 0xFFFFu);
    return h2f(b);
}

// ---------------- dtype detector (parallel): flags[0]=f32, flags[1]=i64 -------
__global__ void k_detect(const unsigned* __restrict__ xw, const unsigned* __restrict__ ew,
                         int* __restrict__ flags) {
    const int t = threadIdx.x;   // 64 lanes
    int lo_nz = 0, huge = 0, hi_nz = 0;
    for (int j = 0; j < 4; ++j) {
        unsigned w = xw[t * 4 + j];
        unsigned lo = w & 0xFFFFu;
        if (lo != 0u) lo_nz = 1;
        if (((lo >> 7) & 0xFFu) >= 0xC0u) huge = 1;
        unsigned eo = ew[(t * 4 + j) * 2 + 1];   // odd 32-bit words of edge array
        if (eo != 0u) hi_nz = 1;
    }
    unsigned long long m_lo = __ballot(lo_nz);
    unsigned long long m_hg = __ballot(huge);
    unsigned long long m_hi = __ballot(hi_nz);
    if (t == 0) {
        flags[0] = (m_lo == 0ull || m_hg != 0ull) ? 1 : 0;   // all-lo-zero or huge => f32
        flags[1] = (m_hi == 0ull) ? 1 : 0;                   // all odd words zero => i64
    }
}

// ---------------- prep: W1T[n][k], W2T[n][k] as bf16 --------------------------
__global__ void k_prep(const void* W1v, const void* W2v, const int* __restrict__ flags,
                       unsigned short* __restrict__ W1T, unsigned short* __restrict__ W2T) {
    const int t = threadIdx.x;
    const int f32in = flags[0];
    const unsigned short* w1g = (const unsigned short*)W1v;
    const float* w1f = (const float*)W1v;
    for (int i = 0; i < 64; ++i) {
        int id = i * 256 + t;                 // n*128+k
        int n = id >> 7, k = id & 127;
        W1T[id] = f32in ? f2bf_bits(w1f[k * 128 + n]) : w1g[k * 128 + n];
    }
    const unsigned short* w2g = (const unsigned short*)W2v;
    const float* w2f = (const float*)W2v;
    for (int i = 0; i < 16; ++i) {
        int id = i * 256 + t;                 // n*128+k  (n<32)
        int n = id >> 7, k = id & 127;
        W2T[id] = f32in ? f2bf_bits(w2f[k * 32 + n]) : w2g[k * 32 + n];
    }
}

// ---------------- edge decode helpers ----------------------------------------
template <typename IT>
__device__ __forceinline__ void get_sd(const IT* __restrict__ ei, int idx, int& s, int& d) {
    if (idx < EE) { s = (int)ei[idx]; d = (int)ei[EE + idx]; }
    else          { s = d = idx - EE; }
}
template <typename IT>
__device__ __forceinline__ int dst_of(const IT* __restrict__ ei, int idx) {
    return idx < EE ? (int)ei[EE + idx] : idx - EE;
}

// ---------------- Layer 1 linear via MFMA: h1(bf16) = x @ W1, + logits --------
#define MROWS 64
#define LDK 136   // padded LDS row stride (elements) -> 272 B, 16B-aligned frags

__global__ __launch_bounds__(256) void k_lin1_mfma(
    const void* xv, const unsigned short* __restrict__ W1T,
    const void* as1v, const void* ad1v,
    const int* __restrict__ flags, bf16* __restrict__ h1,
    float* __restrict__ als, float* __restrict__ ald)
{
    __shared__ __align__(16) char smem[(MROWS + 128) * LDK * 2];  // 52,224 B
    unsigned short* xs  = (unsigned short*)smem;       // [MROWS][LDK] bf16 bits
    unsigned short* w1t = xs + MROWS * LDK;            // [128][LDK]   (n-major)
    float* hs = (float*)smem;                          // phase2 alias: [MROWS][132]
    __shared__ float sa[F1], sd[F1];

    const int t = threadIdx.x;
    const int row0 = blockIdx.x * MROWS;
    const int f32in = flags[0];

    if (t < F1) {
        sa[t] = f32in ? ((const float*)as1v)[t] : cvt(((const bf16*)as1v)[t]);
        sd[t] = f32in ? ((const float*)ad1v)[t] : cvt(((const bf16*)ad1v)[t]);
    }
    if (!f32in) {
        const uint4* xg = (const uint4*)xv;            // 16 B = 8 bf16
        for (int i = 0; i < 4; ++i) {
            int id = i * 256 + t;                      // 0..1023
            int m = id >> 4, seg = id & 15;
            int gr = row0 + m;
            uint4 val = (gr < NN) ? xg[(size_t)gr * 16 + seg] : make_uint4(0, 0, 0, 0);
            *(uint4*)&xs[m * LDK + seg * 8] = val;
        }
    } else {
        const float* xf = (const float*)xv;
        for (int i = 0; i < 32; ++i) {
            int id = i * 256 + t;
            int m = id >> 7, c = id & 127;
            int gr = row0 + m;
            xs[m * LDK + c] = (gr < NN) ? f2bf_bits(xf[(size_t)gr * 128 + c]) : 0;
        }
    }
    {
        const uint4* wg = (const uint4*)W1T;           // [128][16] uint4, n-major
        for (int i = 0; i < 8; ++i) {
            int id = i * 256 + t;                      // 0..2047 = n*16+seg
            int n = id >> 4, seg = id & 15;
            *(uint4*)&w1t[n * LDK + seg * 8] = wg[id];
        }
    }
    __syncthreads();

    const int wave = t >> 6, lane = t & 63, quad = lane >> 4, l16 = lane & 15;
    f32x4 acc[8];
#pragma unroll
    for (int ni = 0; ni < 8; ++ni) acc[ni] = (f32x4){0.f, 0.f, 0.f, 0.f};

    const int arow = wave * 16 + l16;
#pragma unroll
    for (int kc = 0; kc < 4; ++kc) {
        int ko = kc * 32 + quad * 8;
        bf16x8 av = *(const bf16x8*)&xs[arow * LDK + ko];
#pragma unroll
        for (int ni = 0; ni < 8; ++ni) {
            bf16x8 bv = *(const bf16x8*)&w1t[(ni * 16 + l16) * LDK + ko];
            acc[ni] = __builtin_amdgcn_mfma_f32_16x16x32_bf16(av, bv, acc[ni], 0, 0, 0);
        }
    }
    __syncthreads();   // staging LDS dead; reuse as hs

#pragma unroll
    for (int ni = 0; ni < 8; ++ni)
#pragma unroll
        for (int r = 0; r < 4; ++r) {
            int m = wave * 16 + quad * 4 + r;          // C/D: row=quad*4+reg, col=l16
            hs[m * 132 + ni * 16 + l16] = acc[ni][r];
        }
    __syncthreads();

    for (int i = 0; i < 32; ++i) {
        int id = i * 256 + t;                          // 0..8191
        int m = id >> 7, c = id & 127;
        int gr = row0 + m;
        if (gr < NN)
            h1[(size_t)gr * 128 + c] = __float2bfloat16(hs[m * 132 + c]);
    }
    {
        int m = t >> 2, h = t & 3;                     // 64 nodes x 4 heads
        int gr = row0 + m;
        if (gr < NN) {
            float ps = 0.f, pd = 0.f;
#pragma unroll
            for (int j = 0; j < 32; ++j) {
                float v = hs[m * 132 + h * 32 + j];
                ps += v * sa[h * 32 + j];
                pd += v * sd[h * 32 + j];
            }
            als[gr * 4 + h] = ps;
            ald[gr * 4 + h] = pd;
        }
    }
}

// ---------------- CSR build: histogram(+rank) + 3-phase scan ------------------
#define SCAN_B 196   // ceil(NN/256)

__global__ void k_hist(const void* ei, const int* __restrict__ flags,
                       int* __restrict__ counts, int* __restrict__ rank) {
    int idx = blockIdx.x * blockDim.x + threadIdx.x;
    if (idx >= EN) return;
    int d = flags[1] ? dst_of<long long>((const long long*)ei, idx)
                     : dst_of<int>((const int*)ei, idx);
    rank[idx] = atomicAdd(&counts[d], 1);
}

__global__ void k_scanA(const int* __restrict__ counts, int* __restrict__ bsum) {
    __shared__ int sh[256];
    int i = blockIdx.x * 256 + threadIdx.x;
    sh[threadIdx.x] = (i < NN) ? counts[i] : 0;
    __syncthreads();
    for (int off = 128; off > 0; off >>= 1) {
        if (threadIdx.x < off) sh[threadIdx.x] += sh[threadIdx.x + off];
        __syncthreads();
    }
    if (threadIdx.x == 0) bsum[blockIdx.x] = sh[0];
}

__global__ void k_scanB(const int* __restrict__ bsum, int* __restrict__ bbase) {
    __shared__ int sh[256];
    int t = threadIdx.x;
    int v = (t < SCAN_B) ? bsum[t] : 0;
    sh[t] = v;
    __syncthreads();
    for (int off = 1; off < 256; off <<= 1) {
        int u = (t >= off) ? sh[t - off] : 0;
        __syncthreads();
        sh[t] += u;
        __syncthreads();
    }
    if (t < SCAN_B) bbase[t] = sh[t] - v;   // exclusive prefix of block sums
}

__global__ void k_scanC(const int* __restrict__ counts, const int* __restrict__ bbase,
                        int* __restrict__ offsets) {
    __shared__ int sh[256];
    int t = threadIdx.x;
    int i = blockIdx.x * 256 + t;
    int v = (i < NN) ? counts[i] : 0;
    sh[t] = v;
    __syncthreads();
    for (int off = 1; off < 256; off <<= 1) {
        int u = (t >= off) ? sh[t - off] : 0;
        __syncthreads();
        sh[t] += u;
        __syncthreads();
    }
    if (i < NN) {
        offsets[i] = bbase[blockIdx.x] + sh[t] - v;
    } else if (i == NN) {
        offsets[NN] = EN;                    // total is static
    }
}

// ---- scatter (no atomic): one 16B record/edge = {src, exp01, exp23, 0} -------
__global__ void k_scatter(const void* ei, const int* __restrict__ flags,
                          const int* __restrict__ offsets, const int* __restrict__ rank,
                          const float4* __restrict__ als, const float4* __restrict__ ald,
                          uint4* __restrict__ rec) {
    int idx = blockIdx.x * blockDim.x + threadIdx.x;
    if (idx >= EN) return;
    int s, d;
    if (flags[1]) get_sd<long long>((const long long*)ei, idx, s, d);
    else          get_sd<int>((const int*)ei, idx, s, d);
    int slot = offsets[d] + rank[idx];
    float4 a = als[s], b = ald[d];
    float e0 = a.x + b.x, e1 = a.y + b.y, e2 = a.z + b.z, e3 = a.w + b.w;
    e0 = e0 > 0.f ? e0 : NEG * e0;
    e1 = e1 > 0.f ? e1 : NEG * e1;
    e2 = e2 > 0.f ? e2 : NEG * e2;
    e3 = e3 > 0.f ? e3 : NEG * e3;
    unsigned w0 = (unsigned)f2h_bits(__expf(e0)) | ((unsigned)f2h_bits(__expf(e1)) << 16);
    unsigned w1 = (unsigned)f2h_bits(__expf(e2)) | ((unsigned)f2h_bits(__expf(e3)) << 16);
    rec[slot] = make_uint4((unsigned)s, w0, w1, 0u);
}

// ---- Layer 1 aggregate: 1 wave/node, half-wave/edge, unroll x4, rec stream,
//      fused bias+ELU, bf16 output (hm) ----------------------------------------
__global__ __launch_bounds__(256) void k_agg1(
    const int* __restrict__ offsets, const uint4* __restrict__ rec,
    const bf16* __restrict__ h1, const void* b1v, const int* __restrict__ flags,
    uint2* __restrict__ hm)
{
    const int lane = threadIdx.x & 63;
    const int d = blockIdx.x * 4 + (threadIdx.x >> 6);
    const int q = lane >> 5;           // half: even/odd edges
    const int u = lane & 31;           // uint2 index in row -> channels 4u..4u+3
    const int h = u >> 3;              // head of these channels
    const int start = offsets[d], end = offsets[d + 1];
    const uint2* rows = (const uint2*)h1;   // 32 uint2 per 256 B row

    float A0[4] = {0,0,0,0}, A1[4] = {0,0,0,0}, A2[4] = {0,0,0,0}, A3[4] = {0,0,0,0};
    float D[4] = {0,0,0,0};
    int e = start + q;
    for (; e + 6 < end; e += 8) {
        uint4 r0 = rec[e],     r1 = rec[e + 2];
        uint4 r2 = rec[e + 4], r3 = rec[e + 6];
        float x0 = rec_exp(r0, h), x1 = rec_exp(r1, h);
        float x2 = rec_exp(r2, h), x3 = rec_exp(r3, h);
        uint2 u0 = rows[r0.x * 32 + u], u1 = rows[r1.x * 32 + u];
        uint2 u2 = rows[r2.x * 32 + u], u3 = rows[r3.x * 32 + u];
        A0[0] += x0 * bflo(u0.x); A0[1] += x0 * bfhi(u0.x);
        A0[2] += x0 * bflo(u0.y); A0[3] += x0 * bfhi(u0.y); D[0] += x0;
        A1[0] += x1 * bflo(u1.x); A1[1] += x1 * bfhi(u1.x);
        A1[2] += x1 * bflo(u1.y); A1[3] += x1 * bfhi(u1.y); D[1] += x1;
        A2[0] += x2 * bflo(u2.x); A2[1] += x2 * bfhi(u2.x);
        A2[2] += x2 * bflo(u2.y); A2[3] += x2 * bfhi(u2.y); D[2] += x2;
        A3[0] += x3 * bflo(u3.x); A3[1] += x3 * bfhi(u3.x);
        A3[2] += x3 * bflo(u3.y); A3[3] += x3 * bfhi(u3.y); D[3] += x3;
    }
    for (; e < end; e += 2) {
        uint4 r0 = rec[e];
        float x0 = rec_exp(r0, h);
        uint2 u0 = rows[r0.x * 32 + u];
        A0[0] += x0 * bflo(u0.x); A0[1] += x0 * bfhi(u0.x);
        A0[2] += x0 * bflo(u0.y); A0[3] += x0 * bfhi(u0.y); D[0] += x0;
    }
    float a0 = A0[0] + A1[0] + A2[0] + A3[0];
    float a1 = A0[1] + A1[1] + A2[1] + A3[1];
    float a2 = A0[2] + A1[2] + A2[2] + A3[2];
    float a3 = A0[3] + A1[3] + A2[3] + A3[3];
    float dsum = D[0] + D[1] + D[2] + D[3];
    a0 += __shfl_xor(a0, 32); a1 += __shfl_xor(a1, 32);
    a2 += __shfl_xor(a2, 32); a3 += __shfl_xor(a3, 32);
    dsum += __shfl_xor(dsum, 32);
    if (q == 0) {
        float inv = 1.f / (dsum + 1e-16f);
        float bb0, bb1, bb2, bb3;
        if (flags[0]) {
            float4 bb = ((const float4*)b1v)[u];
            bb0 = bb.x; bb1 = bb.y; bb2 = bb.z; bb3 = bb.w;
        } else {
            uint2 ub = ((const uint2*)b1v)[u];
            bb0 = bflo(ub.x); bb1 = bfhi(ub.x); bb2 = bflo(ub.y); bb3 = bfhi(ub.y);
        }
        float v0 = a0 * inv + bb0, v1 = a1 * inv + bb1;
        float v2 = a2 * inv + bb2, v3 = a3 * inv + bb3;
        v0 = v0 > 0.f ? v0 : (__expf(v0) - 1.f);   // ELU
        v1 = v1 > 0.f ? v1 : (__expf(v1) - 1.f);
        v2 = v2 > 0.f ? v2 : (__expf(v2) - 1.f);
        v3 = v3 > 0.f ? v3 : (__expf(v3) - 1.f);
        unsigned w0 = (unsigned)f2bf_bits(v0) | ((unsigned)f2bf_bits(v1) << 16);
        unsigned w1 = (unsigned)f2bf_bits(v2) | ((unsigned)f2bf_bits(v3) << 16);
        hm[(size_t)d * 32 + u] = make_uint2(w0, w1);
    }
}

// ---------------- Mid via MFMA: h2(f16) = hm @ W2, + layer-2 logits -----------
__global__ __launch_bounds__(256) void k_mid_mfma(
    const bf16* __restrict__ hm, const unsigned short* __restrict__ W2T,
    const void* as2v, const void* ad2v,
    const int* __restrict__ flags, unsigned short* __restrict__ h2,
    float* __restrict__ als2, float* __restrict__ ald2)
{
    __shared__ __align__(16) unsigned short hs[MROWS * LDK];   // 17,408 B
    __shared__ __align__(16) unsigned short w2t[32 * LDK];     // 8,704 B
    __shared__ float sa2[HID], sd2[HID];

    const int t = threadIdx.x;
    const int row0 = blockIdx.x * MROWS;
    const int f32in = flags[0];

    if (t < HID) {
        sa2[t] = f32in ? ((const float*)as2v)[t] : cvt(((const bf16*)as2v)[t]);
        sd2[t] = f32in ? ((const float*)ad2v)[t] : cvt(((const bf16*)ad2v)[t]);
    }
    {
        const uint4* hg = (const uint4*)hm;
        for (int i = 0; i < 4; ++i) {
            int id = i * 256 + t;                      // 0..1023
            int m = id >> 4, seg = id & 15;
            int gr = row0 + m;
            uint4 val = (gr < NN) ? hg[(size_t)gr * 16 + seg] : make_uint4(0, 0, 0, 0);
            *(uint4*)&hs[m * LDK + seg * 8] = val;
        }
        const uint4* wg = (const uint4*)W2T;           // [32][16] uint4, n-major
        for (int i = 0; i < 2; ++i) {
            int id = i * 256 + t;                      // 0..511 = n*16+seg
            int n = id >> 4, seg = id & 15;
            *(uint4*)&w2t[n * LDK + seg * 8] = wg[id];
        }
    }
    __syncthreads();

    const int wave = t >> 6, lane = t & 63, quad = lane >> 4, l16 = lane & 15;
    f32x4 acc[2];
    acc[0] = (f32x4){0.f, 0.f, 0.f, 0.f};
    acc[1] = (f32x4){0.f, 0.f, 0.f, 0.f};
    const int arow = wave * 16 + l16;
#pragma unroll
    for (int kc = 0; kc < 4; ++kc) {
        int ko = kc * 32 + quad * 8;
        bf16x8 av = *(const bf16x8*)&hs[arow * LDK + ko];
#pragma unroll
        for (int ni = 0; ni < 2; ++ni) {
            bf16x8 bv = *(const bf16x8*)&w2t[(ni * 16 + l16) * LDK + ko];
            acc[ni] = __builtin_amdgcn_mfma_f32_16x16x32_bf16(av, bv, acc[ni], 0, 0, 0);
        }
    }

    // h2 (f16) stores straight from registers (C/D: row=quad*4+r, col=ni*16+l16)
#pragma unroll
    for (int ni = 0; ni < 2; ++ni)
#pragma unroll
        for (int r = 0; r < 4; ++r) {
            int gr = row0 + wave * 16 + quad * 4 + r;
            if (gr < NN) h2[(size_t)gr * 32 + ni * 16 + l16] = f2h_bits(acc[ni][r]);
        }

    // logits: per-row dot with a_src2/a_dst2, 16-lane butterfly reduction
    float ps[4], pd[4];
#pragma unroll
    for (int r = 0; r < 4; ++r) {
        ps[r] = acc[0][r] * sa2[l16] + acc[1][r] * sa2[16 + l16];
        pd[r] = acc[0][r] * sd2[l16] + acc[1][r] * sd2[16 + l16];
    }
#pragma unroll
    for (int mask = 1; mask < 16; mask <<= 1)
#pragma unroll
        for (int r = 0; r < 4; ++r) {
            ps[r] += __shfl_xor(ps[r], mask);
            pd[r] += __shfl_xor(pd[r], mask);
        }
    if (l16 == 0) {
#pragma unroll
        for (int r = 0; r < 4; ++r) {
            int gr = row0 + wave * 16 + quad * 4 + r;
            if (gr < NN) { als2[gr] = ps[r]; ald2[gr] = pd[r]; }
        }
    }
}

// ---- Layer 2 aggregate: 1 wave/node, 16 lanes/edge (q=0..3), unroll x2 -------
__global__ __launch_bounds__(256) void k_agg2(
    const int* __restrict__ offsets, const uint4* __restrict__ rec,
    const float* __restrict__ als2, const float* __restrict__ ald2,
    const unsigned* __restrict__ h2,   // f16 pairs, 16 per row
    const void* b2v, const int* __restrict__ flags, void* out)
{
    const int lane = threadIdx.x & 63;
    const int node = blockIdx.x * 4 + (threadIdx.x >> 6);
    const int q = lane >> 4;           // 0..3: edge sub-stream
    const int u = lane & 15;           // uint index: channels 2u, 2u+1
    const int start = offsets[node], end = offsets[node + 1];
    const float adv = ald2[node];

    float A0 = 0.f, A1 = 0.f, B0 = 0.f, B1 = 0.f, D0 = 0.f, D1 = 0.f;
    int e = start + q;
    for (; e + 4 < end; e += 8) {
        int s0 = (int)rec[e].x, s1 = (int)rec[e + 4].x;
        float e0 = als2[s0] + adv, e1 = als2[s1] + adv;
        e0 = e0 > 0.f ? e0 : NEG * e0;
        e1 = e1 > 0.f ? e1 : NEG * e1;
        float x0 = __expf(e0), x1 = __expf(e1);
        unsigned w0 = h2[s0 * 16 + u];
        unsigned w1 = h2[s1 * 16 + u];
        A0 += x0 * h2f((unsigned short)(w0 & 0xFFFFu));
        A1 += x0 * h2f((unsigned short)(w0 >> 16));  D0 += x0;
        B0 += x1 * h2f((unsigned short)(w1 & 0xFFFFu));
        B1 += x1 * h2f((unsigned short)(w1 >> 16));  D1 += x1;
    }
    for (; e < end; e += 4) {
        int s0 = (int)rec[e].x;
        float e0 = als2[s0] + adv;
        e0 = e0 > 0.f ? e0 : NEG * e0;
        float x0 = __expf(e0);
        unsigned w0 = h2[s0 * 16 + u];
        A0 += x0 * h2f((unsigned short)(w0 & 0xFFFFu));
        A1 += x0 * h2f((unsigned short)(w0 >> 16));  D0 += x0;
    }
    float a0 = A0 + B0, a1 = A1 + B1, dsum = D0 + D1;
    a0 += __shfl_xor(a0, 16); a1 += __shfl_xor(a1, 16); dsum += __shfl_xor(dsum, 16);
    a0 += __shfl_xor(a0, 32); a1 += __shfl_xor(a1, 32); dsum += __shfl_xor(dsum, 32);
    if (q == 0) {
        float inv = 1.f / (dsum + 1e-16f);
        float r0 = a0 * inv, r1 = a1 * inv;
        if (flags[0]) {
            float2 bb = ((const float2*)b2v)[u];
            ((float2*)out)[(size_t)node * 16 + u] = make_float2(r0 + bb.x, r1 + bb.y);
        } else {
            unsigned ub = ((const unsigned*)b2v)[u];
            r0 += bflo(ub); r1 += bfhi(ub);
            ((unsigned*)out)[(size_t)node * 16 + u] =
                (unsigned)f2bf_bits(r0) | ((unsigned)f2bf_bits(r1) << 16);
        }
    }
}

extern "C" void kernel_launch(void* const* d_in, const int* in_sizes, int n_in,
                              void* d_out, int out_size, void* d_ws, size_t ws_size,
                              hipStream_t stream) {
    const void* x    = d_in[0];
    const void* ei   = d_in[1];
    const void* W1   = d_in[2];
    const void* a_s1 = d_in[3];
    const void* a_d1 = d_in[4];
    const void* b1   = d_in[5];
    const void* W2   = d_in[6];
    const void* a_s2 = d_in[7];
    const void* a_d2 = d_in[8];
    const void* b2v  = d_in[9];

    // ---- workspace layout (~41.7 MB) ----
    int*   flags  = (int*)d_ws;
    char*  pc     = (char*)d_ws + 256;
    uint2* hm     = (uint2*)pc;            pc += (size_t)NN * 32 * 8;   // bf16 [NN][128], 12.8 MB
    int*   rank   = (int*)hm;              // alias: rank ∈ [hist,scatter], hm ∈ [agg1,mid]
    bf16*  h1     = (bf16*)pc;             pc += (size_t)NN * F1 * 2;   // 12.8 MB
    unsigned short* h2 = (unsigned short*)h1;  // f16 [NN][32] alias (h1 dead after agg1)
    uint4* rec    = (uint4*)pc;            pc += (size_t)EN * 16;      // 13.6 MB
    float* al_s1  = (float*)pc;            pc += (size_t)NN * HEADS * 4;
    float* al_d1  = (float*)pc;            pc += (size_t)NN * HEADS * 4;
    float* al_s2  = (float*)pc;            pc += (size_t)NN * 4;
    float* al_d2  = (float*)pc;            pc += (size_t)NN * 4;
    int*   offs   = (int*)pc;              pc += (size_t)(NN + 4) * 4;
    int*   counts = (int*)pc;              pc += (size_t)NN * 4;
    unsigned short* W1T = (unsigned short*)pc; pc += (size_t)128 * 128 * 2;
    unsigned short* W2T = (unsigned short*)pc; pc += (size_t)32 * 128 * 2;
    int*   bsum   = (int*)pc;              pc += SCAN_B * 4;
    int*   bbase  = (int*)pc;              pc += SCAN_B * 4;

    hipMemsetAsync(counts, 0, (size_t)NN * sizeof(int), stream);

    k_detect<<<1, 64, 0, stream>>>((const unsigned*)x, (const unsigned*)ei, flags);
    k_prep<<<1, 256, 0, stream>>>(W1, W2, flags, W1T, W2T);
    k_hist<<<(EN + 255) / 256, 256, 0, stream>>>(ei, flags, counts, rank);
    k_scanA<<<SCAN_B, 256, 0, stream>>>(counts, bsum);
    k_scanB<<<1, 256, 0, stream>>>(bsum, bbase);
    k_scanC<<<SCAN_B, 256, 0, stream>>>(counts, bbase, offs);
    k_lin1_mfma<<<(NN + MROWS - 1) / MROWS, 256, 0, stream>>>(x, W1T, a_s1, a_d1,
                                                              flags, h1, al_s1, al_d1);
    k_scatter<<<(EN + 255) / 256, 256, 0, stream>>>(ei, flags, offs, rank,
                                                    (const float4*)al_s1,
                                                    (const float4*)al_d1, rec);
    k_agg1<<<NN / 4, 256, 0, stream>>>(offs, rec, h1, b1, flags, hm);
    k_mid_mfma<<<(NN + MROWS - 1) / MROWS, 256, 0, stream>>>((const bf16*)hm, W2T, a_s2,
                                                             a_d2, flags, h2, al_s2, al_d2);
    k_agg2<<<NN / 4, 256, 0, stream>>>(offs, rec, al_s2, al_d2, (const unsigned*)h2,
                                       b2v, flags, d_out);
}